// Round 22
// baseline (275.888 us; speedup 1.0000x reference)
//
#include <hip/hip_runtime.h>
#include <hip/hip_fp16.h>

#define NN 20000      // nodes
#define NE 640000     // edges (without self loops)
#define NEE 660000    // edges + self loops
#define NP 200000     // drug pairs
#define NEG 0.2f      // leaky relu slope

typedef _Float16 f16;
typedef __attribute__((ext_vector_type(4))) _Float16 f16x4;
typedef __attribute__((ext_vector_type(8))) _Float16 f16x8;
typedef __attribute__((ext_vector_type(4))) float f32x4;

// ---------------- CSR build ----------------
__global__ void k_hist(const int* __restrict__ ei, int* __restrict__ cnt) {
  int i = blockIdx.x * 256 + threadIdx.x;
  if (i >= NEE) return;
  int d = (i < NE) ? ei[NE + i] : (i - NE);
  atomicAdd(&cnt[d], 1);
}

__global__ __launch_bounds__(1024) void k_scan(const int* __restrict__ cnt, int* __restrict__ rp) {
  __shared__ int ps[1024];
  const int CH = 20;  // 1024*20 = 20480 >= 20000
  int t = threadIdx.x;
  int lo = t * CH, hi = lo + CH;
  if (hi > NN) hi = NN;
  if (lo > NN) lo = NN;
  int s = 0;
  for (int i = lo; i < hi; ++i) s += cnt[i];
  ps[t] = s;
  __syncthreads();
  for (int off = 1; off < 1024; off <<= 1) {
    int v = (t >= off) ? ps[t - off] : 0;
    __syncthreads();
    ps[t] += v;
    __syncthreads();
  }
  int run = (t > 0) ? ps[t - 1] : 0;
  for (int i = lo; i < hi; ++i) { rp[i] = run; run += cnt[i]; }
  if (t == 1023) rp[NN] = ps[1023];
}

__global__ void k_scatter(const int* __restrict__ ei, const int* __restrict__ rp,
                          int* __restrict__ cur, int* __restrict__ col,
                          int* __restrict__ dstv) {
  int i = blockIdx.x * 256 + threadIdx.x;
  if (i >= NEE) return;
  int s, d;
  if (i < NE) { s = ei[i]; d = ei[NE + i]; } else { s = i - NE; d = s; }
  int pos = atomicAdd(&cur[d], 1);
  col[rp[d] + pos] = s;
  dstv[rp[d] + pos] = d;
}

// ---------------- prep: all weight conversions (W1T, W2T, Wp2Th, bp2p) ----------------
__global__ void k_prep(const float* __restrict__ Wp2, const float* __restrict__ bp2,
                       const float* __restrict__ W2, const float* __restrict__ W1,
                       f16* __restrict__ Wp2Th, float* __restrict__ bp2p,
                       f16* __restrict__ W2T, f16* __restrict__ W1T) {
  int i = blockIdx.x * 256 + threadIdx.x;
  if (i < 96 * 64) {
    int o = i >> 6, t = i & 63;
    Wp2Th[o * 64 + t] = (o < 86) ? (f16)Wp2[t * 86 + o] : (f16)0.f;
  }
  if (i < 96) bp2p[i] = (i < 86) ? bp2[i] : 0.f;
  if (i < 64 * 256) {
    int n = i >> 8, k = i & 255;
    W2T[n * 256 + k] = (f16)W2[k * 64 + n];
  }
  if (i < 256 * 256) {
    int r = i >> 8, c = i & 255;
    W1T[c * 256 + r] = (f16)W1[i];
  }
}

// ---------------- GEMM1 v4 (MFMA): h1 = x @ W1, fp32 x staged+converted in-kernel --------
__global__ __launch_bounds__(256) void k_gemm1(
    const float* __restrict__ x, const f16* __restrict__ W1T,
    const float* __restrict__ as1, const float* __restrict__ ad1,
    __half* __restrict__ h1h16, float* __restrict__ AS1, float* __restrict__ AD1) {
  __shared__ f16 xs[16][264];     // 16 rows x 256 k, row stride 528B
  int tid = threadIdx.x;
  int base = blockIdx.x * 16;
  {
    int r = tid >> 4, ch = tid & 15;   // thread converts 16 floats (64B) of one row
    const float4* src = (const float4*)(x + (size_t)(base + r) * 256 + ch * 16);
    float4 a0 = src[0], a1 = src[1], a2 = src[2], a3 = src[3];
    f16 tmp[16];
    tmp[0] = (f16)a0.x; tmp[1] = (f16)a0.y; tmp[2] = (f16)a0.z; tmp[3] = (f16)a0.w;
    tmp[4] = (f16)a1.x; tmp[5] = (f16)a1.y; tmp[6] = (f16)a1.z; tmp[7] = (f16)a1.w;
    tmp[8] = (f16)a2.x; tmp[9] = (f16)a2.y; tmp[10] = (f16)a2.z; tmp[11] = (f16)a2.w;
    tmp[12] = (f16)a3.x; tmp[13] = (f16)a3.y; tmp[14] = (f16)a3.z; tmp[15] = (f16)a3.w;
    *(uint4*)&xs[r][ch * 16] = *(uint4*)&tmp[0];
    *(uint4*)&xs[r][ch * 16 + 8] = *(uint4*)&tmp[8];
  }
  __syncthreads();
  int wv = tid >> 6, lane = tid & 63;
  int head = wv;
  int lr = lane & 15, lk = lane >> 4;
  f32x4 acc[4] = {{0.f,0.f,0.f,0.f},{0.f,0.f,0.f,0.f},{0.f,0.f,0.f,0.f},{0.f,0.f,0.f,0.f}};
#pragma unroll
  for (int k0 = 0; k0 < 256; k0 += 32) {
    f16x8 a = *(const f16x8*)&xs[lr][k0 + lk * 8];
#pragma unroll
    for (int nt = 0; nt < 4; ++nt) {
      int n = head * 64 + nt * 16 + lr;
      f16x8 b = *(const f16x8*)(W1T + (size_t)n * 256 + k0 + lk * 8);
      acc[nt] = __builtin_amdgcn_mfma_f32_16x16x32_f16(a, b, acc[nt], 0, 0, 0);
    }
  }
#pragma unroll
  for (int nt = 0; nt < 4; ++nt) {
    int cc = nt * 16 + lr;
#pragma unroll
    for (int r = 0; r < 4; ++r) {
      int row = lk * 4 + r;
      h1h16[((size_t)head * NN + base + row) * 64 + cc] = __float2half(acc[nt][r]);
    }
  }
#pragma unroll
  for (int r = 0; r < 4; ++r) {
    float ps = 0.f, pd = 0.f;
#pragma unroll
    for (int nt = 0; nt < 4; ++nt) {
      int cc = nt * 16 + lr;
      ps += acc[nt][r] * as1[head * 64 + cc];
      pd += acc[nt][r] * ad1[head * 64 + cc];
    }
#pragma unroll
    for (int off = 1; off < 16; off <<= 1) {
      ps += __shfl_xor(ps, off);
      pd += __shfl_xor(pd, off);
    }
    if (lr == 0) {
      int n = base + lk * 4 + r;
      AS1[n * 4 + head] = ps;
      AD1[n * 4 + head] = pd;
    }
  }
}

// ---------------- edge weights layer 1: w1[head][e] = exp(lrelu(AS1[s]+AD1[d])) ----------
__global__ void k_edgew1(const int* __restrict__ col, const int* __restrict__ dstv,
                         const float* __restrict__ AS1, const float* __restrict__ AD1,
                         float* __restrict__ w1) {
  int i = blockIdx.x * 256 + threadIdx.x;
  if (i >= NEE) return;
  int s = col[i], d = dstv[i];
  float4 as = *(const float4*)(AS1 + s * 4);
  float4 ad = *(const float4*)(AD1 + d * 4);
  float e0 = as.x + ad.x, e1 = as.y + ad.y, e2 = as.z + ad.z, e3 = as.w + ad.w;
  e0 = fmaxf(e0, NEG * e0);
  e1 = fmaxf(e1, NEG * e1);
  e2 = fmaxf(e2, NEG * e2);
  e3 = fmaxf(e3, NEG * e3);
  w1[0 * NEE + i] = __expf(e0);
  w1[1 * NEE + i] = __expf(e1);
  w1[2 * NEE + i] = __expf(e2);
  w1[3 * NEE + i] = __expf(e3);
}

// ---------------- GAT layer-1 aggregation v6: 8x8, XCD-pinned, w-stream, fma_mix ---------
// Streams precomputed w1 (identical fp32 values) instead of AS1-gather+lrelu+exp (-7
// ops/iter); fp16 accumulate written as acc += p*(float)h so LLVM folds to
// v_fma_mix_f32 (kills the 8 cvt/iter).
__global__ __launch_bounds__(256, 4) void k_agg1(
    const int* __restrict__ rp, const int* __restrict__ col,
    const float* __restrict__ w1, const __half* __restrict__ h1h16,
    const float* __restrict__ b1, __half* __restrict__ out16) {
  int b = blockIdx.x;
  int xcd = b & 7;
  int head = xcd >> 1;
  int grp = (b >> 3) * 2 + (xcd & 1);      // 0..4999, bijective per head
  int wave = threadIdx.x >> 6, lane = threadIdx.x & 63;
  int n = grp * 4 + wave;
  int g = lane >> 3, c8 = (lane & 7) * 8;  // edge group 0..7, col base (8 fp16 = 16B)
  int e0 = rp[n], e1 = rp[n + 1];
  const __half* hs = h1h16 + (size_t)head * NN * 64;
  const float* wp = w1 + (size_t)head * NEE;
  float acc[8] = {0.f,0.f,0.f,0.f,0.f,0.f,0.f,0.f};
  float den = 0.f;

  int ee = e0 + g;
  bool v = ee < e1;
  int ec = v ? ee : e1 - 1;
  int s = col[ec];
  float pw = v ? wp[ec] : 0.f;

  for (int e = e0; e < e1; e += 8) {
    int een = e + 8 + g;
    bool vn = een < e1;
    int ecn = vn ? een : e1 - 1;
    int sn = col[ecn];
    float pwn = vn ? wp[ecn] : 0.f;
    float4 raw = *(const float4*)(hs + (size_t)s * 64 + c8);   // 16B = 8 fp16
    const f16* hf = (const f16*)&raw;
#pragma unroll
    for (int i = 0; i < 8; ++i) acc[i] += pw * (float)hf[i];   // -> v_fma_mix_f32
    den += pw;
    s = sn; pw = pwn;
  }
#pragma unroll
  for (int i = 0; i < 8; ++i) {
    acc[i] += __shfl_xor(acc[i], 8);
    acc[i] += __shfl_xor(acc[i], 16);
    acc[i] += __shfl_xor(acc[i], 32);
  }
  den += __shfl_xor(den, 8); den += __shfl_xor(den, 16); den += __shfl_xor(den, 32);
  if (lane < 8) {
    float inv = 1.f / den;
    int cbase = head * 64 + lane * 8;
    __half ho[8];
#pragma unroll
    for (int i = 0; i < 8; ++i) {
      float r = acc[i] * inv + b1[cbase + i];
      r = r > 0.f ? r : __expf(r) - 1.f;
      ho[i] = __float2half(r);
    }
    *(uint4*)(out16 + (size_t)n * 256 + cbase) = *(uint4*)&ho[0];
  }
}

// ---------------- GEMM2 v2 (MFMA): h2 = h1act @ W2 ----------------
__global__ __launch_bounds__(256) void k_gemm2(
    const f16* __restrict__ h1a16, const f16* __restrict__ W2T,
    const float* __restrict__ as2, const float* __restrict__ ad2,
    __half* __restrict__ h2h16, float* __restrict__ AS2, float* __restrict__ AD2) {
  __shared__ f16 xs[16][264];
  __shared__ float psL[4][16], pdL[4][16];
  int tid = threadIdx.x;
  int base = blockIdx.x * 16;
  {
    int r = tid >> 4, ch = tid & 15;
    const uint4* src = (const uint4*)(h1a16 + (size_t)(base + r) * 256 + ch * 16);
    uint4 v0 = src[0], v1 = src[1];
    *(uint4*)&xs[r][ch * 16] = v0;
    *(uint4*)&xs[r][ch * 16 + 8] = v1;
  }
  __syncthreads();
  int wv = tid >> 6, lane = tid & 63;
  int lr = lane & 15, lk = lane >> 4;
  f32x4 acc = {0.f, 0.f, 0.f, 0.f};
#pragma unroll
  for (int k0 = 0; k0 < 256; k0 += 32) {
    f16x8 a = *(const f16x8*)&xs[lr][k0 + lk * 8];
    f16x8 b = *(const f16x8*)(W2T + (size_t)(wv * 16 + lr) * 256 + k0 + lk * 8);
    acc = __builtin_amdgcn_mfma_f32_16x16x32_f16(a, b, acc, 0, 0, 0);
  }
  int cc = wv * 16 + lr;
  float asv = as2[cc], adv = ad2[cc];
  float psr[4], pdr[4];
#pragma unroll
  for (int r = 0; r < 4; ++r) {
    int row = lk * 4 + r;
    h2h16[(size_t)(base + row) * 64 + cc] = __float2half(acc[r]);
    float ps = acc[r] * asv, pd = acc[r] * adv;
#pragma unroll
    for (int off = 1; off < 16; off <<= 1) {
      ps += __shfl_xor(ps, off);
      pd += __shfl_xor(pd, off);
    }
    psr[r] = ps; pdr[r] = pd;
  }
  if (lr == 0) {
#pragma unroll
    for (int r = 0; r < 4; ++r) {
      psL[wv][lk * 4 + r] = psr[r];
      pdL[wv][lk * 4 + r] = pdr[r];
    }
  }
  __syncthreads();
  if (tid < 16) {
    AS2[base + tid] = psL[0][tid] + psL[1][tid] + psL[2][tid] + psL[3][tid];
    AD2[base + tid] = pdL[0][tid] + pdL[1][tid] + pdL[2][tid] + pdL[3][tid];
  }
}

// ---------------- edge weights layer 2 ----------------
__global__ void k_edgew2(const int* __restrict__ col, const int* __restrict__ dstv,
                         const float* __restrict__ AS2, const float* __restrict__ AD2,
                         float* __restrict__ w2) {
  int i = blockIdx.x * 256 + threadIdx.x;
  if (i >= NEE) return;
  int s = col[i], d = dstv[i];
  float ev = AS2[s] + AD2[d];
  ev = fmaxf(ev, NEG * ev);
  w2[i] = __expf(ev);
}

// ---------------- GAT layer-2 aggregation v5: 8x8, w-stream, fma_mix ----------------
__global__ __launch_bounds__(256, 4) void k_agg2(
    const int* __restrict__ rp, const int* __restrict__ col,
    const float* __restrict__ w2, const __half* __restrict__ h2h16,
    const float* __restrict__ b2, float* __restrict__ out) {
  int wave = threadIdx.x >> 6, lane = threadIdx.x & 63;
  int n = blockIdx.x * 4 + wave;
  int g = lane >> 3, c8 = (lane & 7) * 8;
  int e0 = rp[n], e1 = rp[n + 1];
  float acc[8] = {0.f,0.f,0.f,0.f,0.f,0.f,0.f,0.f};
  float den = 0.f;

  int ee = e0 + g;
  bool v = ee < e1;
  int ec = v ? ee : e1 - 1;
  int s = col[ec];
  float pw = v ? w2[ec] : 0.f;

  for (int e = e0; e < e1; e += 8) {
    int een = e + 8 + g;
    bool vn = een < e1;
    int ecn = vn ? een : e1 - 1;
    int sn = col[ecn];
    float pwn = vn ? w2[ecn] : 0.f;
    float4 raw = *(const float4*)(h2h16 + (size_t)s * 64 + c8);
    const f16* hf = (const f16*)&raw;
#pragma unroll
    for (int i = 0; i < 8; ++i) acc[i] += pw * (float)hf[i];
    den += pw;
    s = sn; pw = pwn;
  }
#pragma unroll
  for (int i = 0; i < 8; ++i) {
    acc[i] += __shfl_xor(acc[i], 8);
    acc[i] += __shfl_xor(acc[i], 16);
    acc[i] += __shfl_xor(acc[i], 32);
  }
  den += __shfl_xor(den, 8); den += __shfl_xor(den, 16); den += __shfl_xor(den, 32);
  if (lane < 8) {
    float inv = 1.f / den;
    int cbase = lane * 8;
    float o[8];
#pragma unroll
    for (int i = 0; i < 8; ++i) {
      float r = acc[i] * inv + b2[cbase + i];
      o[i] = r > 0.f ? r : __expf(r) - 1.f;
    }
    *(float4*)(out + (size_t)n * 64 + cbase) = *(float4*)&o[0];
    *(float4*)(out + (size_t)n * 64 + cbase + 4) = *(float4*)&o[4];
  }
}

// ---------------- per-node pair-MLP layer-1 precompute ----------------
__global__ __launch_bounds__(128) void k_predot(
    const float* __restrict__ h2a, const float* __restrict__ Wp1,
    const float* __restrict__ bp1, float* __restrict__ AB) {
  __shared__ float xsT[64][20];   // [k][row], 16 rows, pad 20
  int c = threadIdx.x;            // 0..127
  int base = blockIdx.x * 16;
  for (int i = threadIdx.x; i < 16 * 64; i += 128) {
    int r = i >> 6, k = i & 63;
    xsT[k][r] = h2a[(size_t)(base + r) * 64 + k];
  }
  __syncthreads();
  int part = c >> 6, u = c & 63;
  float bv = (part == 0) ? bp1[u] : 0.f;
  float acc[16];
#pragma unroll
  for (int r = 0; r < 16; ++r) acc[r] = bv;
#pragma unroll 2
  for (int k = 0; k < 64; ++k) {
    float wv = Wp1[(size_t)(part * 64 + k) * 64 + u];  // coalesced per half-wave
    const float4* xr = (const float4*)&xsT[k][0];
    float4 x0 = xr[0], x1 = xr[1], x2 = xr[2], x3 = xr[3];
    acc[0] += x0.x * wv; acc[1] += x0.y * wv; acc[2] += x0.z * wv; acc[3] += x0.w * wv;
    acc[4] += x1.x * wv; acc[5] += x1.y * wv; acc[6] += x1.z * wv; acc[7] += x1.w * wv;
    acc[8] += x2.x * wv; acc[9] += x2.y * wv; acc[10] += x2.z * wv; acc[11] += x2.w * wv;
    acc[12] += x3.x * wv; acc[13] += x3.y * wv; acc[14] += x3.z * wv; acc[15] += x3.w * wv;
  }
#pragma unroll
  for (int r = 0; r < 16; ++r) AB[(size_t)(base + r) * 128 + c] = acc[r];
}

// ---------------- pair MLP v13: z-gather + MFMA layer 2 ----------------
__global__ __launch_bounds__(256) void k_pairs(
    const int* __restrict__ pairs, const float* __restrict__ AB,
    const f16* __restrict__ Wp2Th, const float* __restrict__ bp2p,
    float* __restrict__ out) {
  __shared__ f16 zh[64][72];  // [pair][t]
  int tid = threadIdx.x;
  int pp = tid & 63, q = tid >> 6;   // pair within block, z-quarter
  int p = blockIdx.x * 64 + pp;
  int pi = pairs[2 * p], pj = pairs[2 * p + 1];

  // ---- phase 1: z quarter q = relu(A[pi] + B[pj]) -> fp16 LDS  (bp1 folded in A)
  {
    const float4* ar = (const float4*)(AB + (size_t)pi * 128 + q * 16);
    const float4* br = (const float4*)(AB + (size_t)pj * 128 + 64 + q * 16);
    f16 zv[16];
#pragma unroll
    for (int m = 0; m < 4; ++m) {
      float4 a = ar[m], b = br[m];
      zv[m * 4]     = (f16)fmaxf(a.x + b.x, 0.f);
      zv[m * 4 + 1] = (f16)fmaxf(a.y + b.y, 0.f);
      zv[m * 4 + 2] = (f16)fmaxf(a.z + b.z, 0.f);
      zv[m * 4 + 3] = (f16)fmaxf(a.w + b.w, 0.f);
    }
    *(uint4*)&zh[pp][q * 16] = *(uint4*)&zv[0];
    *(uint4*)&zh[pp][q * 16 + 8] = *(uint4*)&zv[8];
  }
  __syncthreads();

  // ---- phase 2: out-tile = z @ Wp2 via MFMA; wave wv owns pairs wv*16..wv*16+15
  int wv = tid >> 6, lane = tid & 63;
  int lr = lane & 15, lk = lane >> 4;
#pragma unroll
  for (int nt = 0; nt < 6; ++nt) {
    f32x4 acc = {0.f, 0.f, 0.f, 0.f};
#pragma unroll
    for (int k0 = 0; k0 < 64; k0 += 32) {
      f16x8 a = *(const f16x8*)&zh[wv * 16 + lr][k0 + lk * 8];
      f16x8 b = *(const f16x8*)(Wp2Th + (size_t)(nt * 16 + lr) * 64 + k0 + lk * 8);
      acc = __builtin_amdgcn_mfma_f32_16x16x32_f16(a, b, acc, 0, 0, 0);
    }
    int o = nt * 16 + lr;
    if (o < 86) {
      float bb = bp2p[o];
#pragma unroll
      for (int r = 0; r < 4; ++r) {
        int pr = blockIdx.x * 64 + wv * 16 + lk * 4 + r;
        out[(size_t)pr * 86 + o] = acc[r] + bb;
      }
    }
  }
}

extern "C" void kernel_launch(void* const* d_in, const int* in_sizes, int n_in,
                              void* d_out, int out_size, void* d_ws, size_t ws_size,
                              hipStream_t stream) {
  (void)in_sizes; (void)n_in; (void)out_size; (void)ws_size;
  const float* x      = (const float*)d_in[0];
  const int*   ei     = (const int*)d_in[1];
  const int*   pairs  = (const int*)d_in[2];
  const float* W1     = (const float*)d_in[3];
  const float* a_src1 = (const float*)d_in[4];
  const float* a_dst1 = (const float*)d_in[5];
  const float* b1     = (const float*)d_in[6];
  const float* W2     = (const float*)d_in[7];
  const float* a_src2 = (const float*)d_in[8];
  const float* a_dst2 = (const float*)d_in[9];
  const float* b2     = (const float*)d_in[10];
  const float* Wp1    = (const float*)d_in[11];
  const float* bp1    = (const float*)d_in[12];
  const float* Wp2    = (const float*)d_in[13];
  const float* bp2    = (const float*)d_in[14];
  float* out = (float*)d_out;

  char* w = (char*)d_ws;
  auto alloc = [&](size_t bytes) -> void* {
    void* pp = (void*)w;
    w += (bytes + 255) & ~(size_t)255;
    return pp;
  };
  __half* h1h16 = (__half*)alloc((size_t)NN * 256 * 2);  // head-major [4][NN][64] fp16
  float*  AS1   = (float*)alloc((size_t)NN * 4 * 4);
  float*  AD1   = (float*)alloc((size_t)NN * 4 * 4);
  __half* h1a16 = (__half*)alloc((size_t)NN * 256 * 2);  // fp16 h1agg (gemm2 input)
  __half* h2h16 = (__half*)alloc((size_t)NN * 64 * 2);   // fp16 gather copy
  float*  AS2   = (float*)alloc((size_t)NN * 4);
  float*  AD2   = (float*)alloc((size_t)NN * 4);
  float*  h2agg = (float*)alloc((size_t)NN * 64 * 4);
  float*  AB    = (float*)alloc((size_t)NN * 128 * 4);
  f16*    W1T   = (f16*)alloc((size_t)256 * 256 * 2);    // fp16 W1 transposed [n][k]
  f16*    Wp2Th = (f16*)alloc((size_t)96 * 64 * 2);      // fp16 Wp2 transposed padded
  float*  bp2p  = (float*)alloc(96 * 4);
  f16*    W2T   = (f16*)alloc((size_t)64 * 256 * 2);     // fp16 W2 transposed [n][k]
  float*  w1    = (float*)alloc((size_t)4 * NEE * 4);    // edge weights layer 1
  float*  w2    = (float*)alloc((size_t)NEE * 4);        // edge weights layer 2
  int*    rp    = (int*)alloc((size_t)(NN + 1) * 4);
  int*    cnt   = (int*)alloc((size_t)NN * 4);
  int*    cur   = (int*)alloc((size_t)NN * 4);
  int*    col   = (int*)alloc((size_t)NEE * 4);
  int*    dstv  = (int*)alloc((size_t)NEE * 4);

  (void)hipMemsetAsync(cnt, 0, (size_t)NN * 4, stream);
  (void)hipMemsetAsync(cur, 0, (size_t)NN * 4, stream);

  const int EB = (NEE + 255) / 256;  // 2579
  k_hist<<<EB, 256, 0, stream>>>(ei, cnt);
  k_scan<<<1, 1024, 0, stream>>>(cnt, rp);
  k_scatter<<<EB, 256, 0, stream>>>(ei, rp, cur, col, dstv);
  k_prep<<<256, 256, 0, stream>>>(Wp2, bp2, W2, W1, Wp2Th, bp2p, W2T, W1T);

  k_gemm1<<<NN / 16, 256, 0, stream>>>(x, W1T, a_src1, a_dst1, h1h16, AS1, AD1);
  k_edgew1<<<EB, 256, 0, stream>>>(col, dstv, AS1, AD1, w1);
  k_agg1<<<NN, 256, 0, stream>>>(rp, col, w1, h1h16, b1, h1a16);

  k_gemm2<<<NN / 16, 256, 0, stream>>>((const f16*)h1a16, W2T, a_src2, a_dst2, h2h16, AS2, AD2);
  k_edgew2<<<EB, 256, 0, stream>>>(col, dstv, AS2, AD2, w2);
  k_agg2<<<NN / 4, 256, 0, stream>>>(rp, col, w2, h2h16, b2, h2agg);

  k_predot<<<NN / 16, 128, 0, stream>>>(h2agg, Wp1, bp1, AB);
  k_pairs<<<NP / 64, 256, 0, stream>>>(pairs, AB, Wp2Th, bp2p, out);
}

// Round 23
// 273.173 us; speedup vs baseline: 1.0099x; 1.0099x over previous
//
#include <hip/hip_runtime.h>
#include <hip/hip_fp16.h>

#define NN 20000      // nodes
#define NE 640000     // edges (without self loops)
#define NEE 660000    // edges + self loops
#define NP 200000     // drug pairs
#define NEG 0.2f      // leaky relu slope
#define NPN 2500      // nodes per XCD pass (NN/8)

typedef _Float16 f16;
typedef __attribute__((ext_vector_type(4))) _Float16 f16x4;
typedef __attribute__((ext_vector_type(8))) _Float16 f16x8;
typedef __attribute__((ext_vector_type(4))) float f32x4;

#define ECHUNK 2048
#define NCHUNK ((NEE + ECHUNK - 1) / ECHUNK)   // 323

// ---------------- CSR build: XCD-pinned dst-region passes ----------------
// Random 4B scatters to col (2.6 MB) from all 8 XCDs caused 13x write amplification
// (round-22: WRITE=67MB, 51us, VALU 0.5%). pass = blockIdx.x&7 lands on XCD 'pass'
// (round-robin dispatch); pass p only touches dst in [p*2500,(p+1)*2500) -> its
// 330KB col region stays in ONE XCD's L2, lines fill completely, single writeback.
__global__ void k_hist(const int* __restrict__ ei, int* __restrict__ cnt) {
  int pass = blockIdx.x & 7;
  int chunk = blockIdx.x >> 3;
  int lo = pass * NPN, hi = lo + NPN;
  int base = chunk * ECHUNK;
#pragma unroll 1
  for (int k = 0; k < ECHUNK; k += 256) {
    int i = base + k + threadIdx.x;
    if (i >= NEE) break;
    int d = (i < NE) ? ei[NE + i] : (i - NE);
    if (d >= lo && d < hi) atomicAdd(&cnt[d], 1);
  }
}

__global__ __launch_bounds__(1024) void k_scan(const int* __restrict__ cnt, int* __restrict__ rp) {
  __shared__ int ps[1024];
  const int CH = 20;  // 1024*20 = 20480 >= 20000
  int t = threadIdx.x;
  int lo = t * CH, hi = lo + CH;
  if (hi > NN) hi = NN;
  if (lo > NN) lo = NN;
  int s = 0;
  for (int i = lo; i < hi; ++i) s += cnt[i];
  ps[t] = s;
  __syncthreads();
  for (int off = 1; off < 1024; off <<= 1) {
    int v = (t >= off) ? ps[t - off] : 0;
    __syncthreads();
    ps[t] += v;
    __syncthreads();
  }
  int run = (t > 0) ? ps[t - 1] : 0;
  for (int i = lo; i < hi; ++i) { rp[i] = run; run += cnt[i]; }
  if (t == 1023) rp[NN] = ps[1023];
}

__global__ void k_scatter(const int* __restrict__ ei, const int* __restrict__ rp,
                          int* __restrict__ cur, int* __restrict__ col) {
  int pass = blockIdx.x & 7;
  int chunk = blockIdx.x >> 3;
  int lo = pass * NPN, hi = lo + NPN;
  int base = chunk * ECHUNK;
#pragma unroll 1
  for (int k = 0; k < ECHUNK; k += 256) {
    int i = base + k + threadIdx.x;
    if (i >= NEE) break;
    int s, d;
    if (i < NE) { s = ei[i]; d = ei[NE + i]; } else { s = i - NE; d = s; }
    if (d >= lo && d < hi) {
      int pos = atomicAdd(&cur[d], 1);
      col[rp[d] + pos] = s;
    }
  }
}

// ---------------- prep: all weight conversions (W1T, W2T, Wp2Th, bp2p) ----------------
__global__ void k_prep(const float* __restrict__ Wp2, const float* __restrict__ bp2,
                       const float* __restrict__ W2, const float* __restrict__ W1,
                       f16* __restrict__ Wp2Th, float* __restrict__ bp2p,
                       f16* __restrict__ W2T, f16* __restrict__ W1T) {
  int i = blockIdx.x * 256 + threadIdx.x;
  if (i < 96 * 64) {
    int o = i >> 6, t = i & 63;
    Wp2Th[o * 64 + t] = (o < 86) ? (f16)Wp2[t * 86 + o] : (f16)0.f;
  }
  if (i < 96) bp2p[i] = (i < 86) ? bp2[i] : 0.f;
  if (i < 64 * 256) {
    int n = i >> 8, k = i & 255;
    W2T[n * 256 + k] = (f16)W2[k * 64 + n];
  }
  if (i < 256 * 256) {
    int r = i >> 8, c = i & 255;
    W1T[c * 256 + r] = (f16)W1[i];
  }
}

// ---------------- GEMM1 v4 (MFMA): h1 = x @ W1, fp32 x staged+converted in-kernel --------
__global__ __launch_bounds__(256) void k_gemm1(
    const float* __restrict__ x, const f16* __restrict__ W1T,
    const float* __restrict__ as1, const float* __restrict__ ad1,
    __half* __restrict__ h1h16, float* __restrict__ AS1, float* __restrict__ AD1) {
  __shared__ f16 xs[16][264];     // 16 rows x 256 k, row stride 528B
  int tid = threadIdx.x;
  int base = blockIdx.x * 16;
  {
    int r = tid >> 4, ch = tid & 15;   // thread converts 16 floats (64B) of one row
    const float4* src = (const float4*)(x + (size_t)(base + r) * 256 + ch * 16);
    float4 a0 = src[0], a1 = src[1], a2 = src[2], a3 = src[3];
    f16 tmp[16];
    tmp[0] = (f16)a0.x; tmp[1] = (f16)a0.y; tmp[2] = (f16)a0.z; tmp[3] = (f16)a0.w;
    tmp[4] = (f16)a1.x; tmp[5] = (f16)a1.y; tmp[6] = (f16)a1.z; tmp[7] = (f16)a1.w;
    tmp[8] = (f16)a2.x; tmp[9] = (f16)a2.y; tmp[10] = (f16)a2.z; tmp[11] = (f16)a2.w;
    tmp[12] = (f16)a3.x; tmp[13] = (f16)a3.y; tmp[14] = (f16)a3.z; tmp[15] = (f16)a3.w;
    *(uint4*)&xs[r][ch * 16] = *(uint4*)&tmp[0];
    *(uint4*)&xs[r][ch * 16 + 8] = *(uint4*)&tmp[8];
  }
  __syncthreads();
  int wv = tid >> 6, lane = tid & 63;
  int head = wv;
  int lr = lane & 15, lk = lane >> 4;
  f32x4 acc[4] = {{0.f,0.f,0.f,0.f},{0.f,0.f,0.f,0.f},{0.f,0.f,0.f,0.f},{0.f,0.f,0.f,0.f}};
#pragma unroll
  for (int k0 = 0; k0 < 256; k0 += 32) {
    f16x8 a = *(const f16x8*)&xs[lr][k0 + lk * 8];
#pragma unroll
    for (int nt = 0; nt < 4; ++nt) {
      int n = head * 64 + nt * 16 + lr;
      f16x8 b = *(const f16x8*)(W1T + (size_t)n * 256 + k0 + lk * 8);
      acc[nt] = __builtin_amdgcn_mfma_f32_16x16x32_f16(a, b, acc[nt], 0, 0, 0);
    }
  }
#pragma unroll
  for (int nt = 0; nt < 4; ++nt) {
    int cc = nt * 16 + lr;
#pragma unroll
    for (int r = 0; r < 4; ++r) {
      int row = lk * 4 + r;
      h1h16[((size_t)head * NN + base + row) * 64 + cc] = __float2half(acc[nt][r]);
    }
  }
#pragma unroll
  for (int r = 0; r < 4; ++r) {
    float ps = 0.f, pd = 0.f;
#pragma unroll
    for (int nt = 0; nt < 4; ++nt) {
      int cc = nt * 16 + lr;
      ps += acc[nt][r] * as1[head * 64 + cc];
      pd += acc[nt][r] * ad1[head * 64 + cc];
    }
#pragma unroll
    for (int off = 1; off < 16; off <<= 1) {
      ps += __shfl_xor(ps, off);
      pd += __shfl_xor(pd, off);
    }
    if (lr == 0) {
      int n = base + lk * 4 + r;
      AS1[n * 4 + head] = ps;
      AD1[n * 4 + head] = pd;
    }
  }
}

// ---------------- edge weights layer 1, node-major (no dstv needed) ----------------
// Wave per node: AD broadcast, AS gather per edge, w-writes contiguous per node.
__global__ __launch_bounds__(256) void k_edgew1(
    const int* __restrict__ rp, const int* __restrict__ col,
    const float* __restrict__ AS1, const float* __restrict__ AD1,
    float* __restrict__ w1) {
  int wave = threadIdx.x >> 6, lane = threadIdx.x & 63;
  int n = blockIdx.x * 4 + wave;
  int e0 = rp[n], e1 = rp[n + 1];
  float4 ad = *(const float4*)(AD1 + n * 4);
  for (int e = e0 + lane; e < e1; e += 64) {
    int s = col[e];
    float4 as = *(const float4*)(AS1 + s * 4);
    float v0 = as.x + ad.x, v1 = as.y + ad.y, v2 = as.z + ad.z, v3 = as.w + ad.w;
    v0 = fmaxf(v0, NEG * v0);
    v1 = fmaxf(v1, NEG * v1);
    v2 = fmaxf(v2, NEG * v2);
    v3 = fmaxf(v3, NEG * v3);
    w1[0 * NEE + e] = __expf(v0);
    w1[1 * NEE + e] = __expf(v1);
    w1[2 * NEE + e] = __expf(v2);
    w1[3 * NEE + e] = __expf(v3);
  }
}

// ---------------- GAT layer-1 aggregation v6: 8x8, XCD-pinned, w-stream, fma_mix ---------
__global__ __launch_bounds__(256, 4) void k_agg1(
    const int* __restrict__ rp, const int* __restrict__ col,
    const float* __restrict__ w1, const __half* __restrict__ h1h16,
    const float* __restrict__ b1, __half* __restrict__ out16) {
  int b = blockIdx.x;
  int xcd = b & 7;
  int head = xcd >> 1;
  int grp = (b >> 3) * 2 + (xcd & 1);      // 0..4999, bijective per head
  int wave = threadIdx.x >> 6, lane = threadIdx.x & 63;
  int n = grp * 4 + wave;
  int g = lane >> 3, c8 = (lane & 7) * 8;  // edge group 0..7, col base (8 fp16 = 16B)
  int e0 = rp[n], e1 = rp[n + 1];
  const __half* hs = h1h16 + (size_t)head * NN * 64;
  const float* wp = w1 + (size_t)head * NEE;
  float acc[8] = {0.f,0.f,0.f,0.f,0.f,0.f,0.f,0.f};
  float den = 0.f;

  int ee = e0 + g;
  bool v = ee < e1;
  int ec = v ? ee : e1 - 1;
  int s = col[ec];
  float pw = v ? wp[ec] : 0.f;

  for (int e = e0; e < e1; e += 8) {
    int een = e + 8 + g;
    bool vn = een < e1;
    int ecn = vn ? een : e1 - 1;
    int sn = col[ecn];
    float pwn = vn ? wp[ecn] : 0.f;
    float4 raw = *(const float4*)(hs + (size_t)s * 64 + c8);   // 16B = 8 fp16
    const f16* hf = (const f16*)&raw;
#pragma unroll
    for (int i = 0; i < 8; ++i) acc[i] += pw * (float)hf[i];   // -> v_fma_mix_f32
    den += pw;
    s = sn; pw = pwn;
  }
#pragma unroll
  for (int i = 0; i < 8; ++i) {
    acc[i] += __shfl_xor(acc[i], 8);
    acc[i] += __shfl_xor(acc[i], 16);
    acc[i] += __shfl_xor(acc[i], 32);
  }
  den += __shfl_xor(den, 8); den += __shfl_xor(den, 16); den += __shfl_xor(den, 32);
  if (lane < 8) {
    float inv = 1.f / den;
    int cbase = head * 64 + lane * 8;
    __half ho[8];
#pragma unroll
    for (int i = 0; i < 8; ++i) {
      float r = acc[i] * inv + b1[cbase + i];
      r = r > 0.f ? r : __expf(r) - 1.f;
      ho[i] = __float2half(r);
    }
    *(uint4*)(out16 + (size_t)n * 256 + cbase) = *(uint4*)&ho[0];
  }
}

// ---------------- GEMM2 v2 (MFMA): h2 = h1act @ W2 ----------------
__global__ __launch_bounds__(256) void k_gemm2(
    const f16* __restrict__ h1a16, const f16* __restrict__ W2T,
    const float* __restrict__ as2, const float* __restrict__ ad2,
    __half* __restrict__ h2h16, float* __restrict__ AS2, float* __restrict__ AD2) {
  __shared__ f16 xs[16][264];
  __shared__ float psL[4][16], pdL[4][16];
  int tid = threadIdx.x;
  int base = blockIdx.x * 16;
  {
    int r = tid >> 4, ch = tid & 15;
    const uint4* src = (const uint4*)(h1a16 + (size_t)(base + r) * 256 + ch * 16);
    uint4 v0 = src[0], v1 = src[1];
    *(uint4*)&xs[r][ch * 16] = v0;
    *(uint4*)&xs[r][ch * 16 + 8] = v1;
  }
  __syncthreads();
  int wv = tid >> 6, lane = tid & 63;
  int lr = lane & 15, lk = lane >> 4;
  f32x4 acc = {0.f, 0.f, 0.f, 0.f};
#pragma unroll
  for (int k0 = 0; k0 < 256; k0 += 32) {
    f16x8 a = *(const f16x8*)&xs[lr][k0 + lk * 8];
    f16x8 b = *(const f16x8*)(W2T + (size_t)(wv * 16 + lr) * 256 + k0 + lk * 8);
    acc = __builtin_amdgcn_mfma_f32_16x16x32_f16(a, b, acc, 0, 0, 0);
  }
  int cc = wv * 16 + lr;
  float asv = as2[cc], adv = ad2[cc];
  float psr[4], pdr[4];
#pragma unroll
  for (int r = 0; r < 4; ++r) {
    int row = lk * 4 + r;
    h2h16[(size_t)(base + row) * 64 + cc] = __float2half(acc[r]);
    float ps = acc[r] * asv, pd = acc[r] * adv;
#pragma unroll
    for (int off = 1; off < 16; off <<= 1) {
      ps += __shfl_xor(ps, off);
      pd += __shfl_xor(pd, off);
    }
    psr[r] = ps; pdr[r] = pd;
  }
  if (lr == 0) {
#pragma unroll
    for (int r = 0; r < 4; ++r) {
      psL[wv][lk * 4 + r] = psr[r];
      pdL[wv][lk * 4 + r] = pdr[r];
    }
  }
  __syncthreads();
  if (tid < 16) {
    AS2[base + tid] = psL[0][tid] + psL[1][tid] + psL[2][tid] + psL[3][tid];
    AD2[base + tid] = pdL[0][tid] + pdL[1][tid] + pdL[2][tid] + pdL[3][tid];
  }
}

// ---------------- edge weights layer 2, node-major ----------------
__global__ __launch_bounds__(256) void k_edgew2(
    const int* __restrict__ rp, const int* __restrict__ col,
    const float* __restrict__ AS2, const float* __restrict__ AD2,
    float* __restrict__ w2) {
  int wave = threadIdx.x >> 6, lane = threadIdx.x & 63;
  int n = blockIdx.x * 4 + wave;
  int e0 = rp[n], e1 = rp[n + 1];
  float adv = AD2[n];
  for (int e = e0 + lane; e < e1; e += 64) {
    int s = col[e];
    float ev = AS2[s] + adv;
    ev = fmaxf(ev, NEG * ev);
    w2[e] = __expf(ev);
  }
}

// ---------------- GAT layer-2 aggregation v5: 8x8, w-stream, fma_mix ----------------
__global__ __launch_bounds__(256, 4) void k_agg2(
    const int* __restrict__ rp, const int* __restrict__ col,
    const float* __restrict__ w2, const __half* __restrict__ h2h16,
    const float* __restrict__ b2, float* __restrict__ out) {
  int wave = threadIdx.x >> 6, lane = threadIdx.x & 63;
  int n = blockIdx.x * 4 + wave;
  int g = lane >> 3, c8 = (lane & 7) * 8;
  int e0 = rp[n], e1 = rp[n + 1];
  float acc[8] = {0.f,0.f,0.f,0.f,0.f,0.f,0.f,0.f};
  float den = 0.f;

  int ee = e0 + g;
  bool v = ee < e1;
  int ec = v ? ee : e1 - 1;
  int s = col[ec];
  float pw = v ? w2[ec] : 0.f;

  for (int e = e0; e < e1; e += 8) {
    int een = e + 8 + g;
    bool vn = een < e1;
    int ecn = vn ? een : e1 - 1;
    int sn = col[ecn];
    float pwn = vn ? w2[ecn] : 0.f;
    float4 raw = *(const float4*)(h2h16 + (size_t)s * 64 + c8);
    const f16* hf = (const f16*)&raw;
#pragma unroll
    for (int i = 0; i < 8; ++i) acc[i] += pw * (float)hf[i];
    den += pw;
    s = sn; pw = pwn;
  }
#pragma unroll
  for (int i = 0; i < 8; ++i) {
    acc[i] += __shfl_xor(acc[i], 8);
    acc[i] += __shfl_xor(acc[i], 16);
    acc[i] += __shfl_xor(acc[i], 32);
  }
  den += __shfl_xor(den, 8); den += __shfl_xor(den, 16); den += __shfl_xor(den, 32);
  if (lane < 8) {
    float inv = 1.f / den;
    int cbase = lane * 8;
    float o[8];
#pragma unroll
    for (int i = 0; i < 8; ++i) {
      float r = acc[i] * inv + b2[cbase + i];
      o[i] = r > 0.f ? r : __expf(r) - 1.f;
    }
    *(float4*)(out + (size_t)n * 64 + cbase) = *(float4*)&o[0];
    *(float4*)(out + (size_t)n * 64 + cbase + 4) = *(float4*)&o[4];
  }
}

// ---------------- per-node pair-MLP layer-1 precompute ----------------
__global__ __launch_bounds__(128) void k_predot(
    const float* __restrict__ h2a, const float* __restrict__ Wp1,
    const float* __restrict__ bp1, float* __restrict__ AB) {
  __shared__ float xsT[64][20];   // [k][row], 16 rows, pad 20
  int c = threadIdx.x;            // 0..127
  int base = blockIdx.x * 16;
  for (int i = threadIdx.x; i < 16 * 64; i += 128) {
    int r = i >> 6, k = i & 63;
    xsT[k][r] = h2a[(size_t)(base + r) * 64 + k];
  }
  __syncthreads();
  int part = c >> 6, u = c & 63;
  float bv = (part == 0) ? bp1[u] : 0.f;
  float acc[16];
#pragma unroll
  for (int r = 0; r < 16; ++r) acc[r] = bv;
#pragma unroll 2
  for (int k = 0; k < 64; ++k) {
    float wv = Wp1[(size_t)(part * 64 + k) * 64 + u];  // coalesced per half-wave
    const float4* xr = (const float4*)&xsT[k][0];
    float4 x0 = xr[0], x1 = xr[1], x2 = xr[2], x3 = xr[3];
    acc[0] += x0.x * wv; acc[1] += x0.y * wv; acc[2] += x0.z * wv; acc[3] += x0.w * wv;
    acc[4] += x1.x * wv; acc[5] += x1.y * wv; acc[6] += x1.z * wv; acc[7] += x1.w * wv;
    acc[8] += x2.x * wv; acc[9] += x2.y * wv; acc[10] += x2.z * wv; acc[11] += x2.w * wv;
    acc[12] += x3.x * wv; acc[13] += x3.y * wv; acc[14] += x3.z * wv; acc[15] += x3.w * wv;
  }
#pragma unroll
  for (int r = 0; r < 16; ++r) AB[(size_t)(base + r) * 128 + c] = acc[r];
}

// ---------------- pair MLP v13: z-gather + MFMA layer 2 ----------------
__global__ __launch_bounds__(256) void k_pairs(
    const int* __restrict__ pairs, const float* __restrict__ AB,
    const f16* __restrict__ Wp2Th, const float* __restrict__ bp2p,
    float* __restrict__ out) {
  __shared__ f16 zh[64][72];  // [pair][t]
  int tid = threadIdx.x;
  int pp = tid & 63, q = tid >> 6;   // pair within block, z-quarter
  int p = blockIdx.x * 64 + pp;
  int pi = pairs[2 * p], pj = pairs[2 * p + 1];

  // ---- phase 1: z quarter q = relu(A[pi] + B[pj]) -> fp16 LDS  (bp1 folded in A)
  {
    const float4* ar = (const float4*)(AB + (size_t)pi * 128 + q * 16);
    const float4* br = (const float4*)(AB + (size_t)pj * 128 + 64 + q * 16);
    f16 zv[16];
#pragma unroll
    for (int m = 0; m < 4; ++m) {
      float4 a = ar[m], b = br[m];
      zv[m * 4]     = (f16)fmaxf(a.x + b.x, 0.f);
      zv[m * 4 + 1] = (f16)fmaxf(a.y + b.y, 0.f);
      zv[m * 4 + 2] = (f16)fmaxf(a.z + b.z, 0.f);
      zv[m * 4 + 3] = (f16)fmaxf(a.w + b.w, 0.f);
    }
    *(uint4*)&zh[pp][q * 16] = *(uint4*)&zv[0];
    *(uint4*)&zh[pp][q * 16 + 8] = *(uint4*)&zv[8];
  }
  __syncthreads();

  // ---- phase 2: out-tile = z @ Wp2 via MFMA; wave wv owns pairs wv*16..wv*16+15
  int wv = tid >> 6, lane = tid & 63;
  int lr = lane & 15, lk = lane >> 4;
#pragma unroll
  for (int nt = 0; nt < 6; ++nt) {
    f32x4 acc = {0.f, 0.f, 0.f, 0.f};
#pragma unroll
    for (int k0 = 0; k0 < 64; k0 += 32) {
      f16x8 a = *(const f16x8*)&zh[wv * 16 + lr][k0 + lk * 8];
      f16x8 b = *(const f16x8*)(Wp2Th + (size_t)(nt * 16 + lr) * 64 + k0 + lk * 8);
      acc = __builtin_amdgcn_mfma_f32_16x16x32_f16(a, b, acc, 0, 0, 0);
    }
    int o = nt * 16 + lr;
    if (o < 86) {
      float bb = bp2p[o];
#pragma unroll
      for (int r = 0; r < 4; ++r) {
        int pr = blockIdx.x * 64 + wv * 16 + lk * 4 + r;
        out[(size_t)pr * 86 + o] = acc[r] + bb;
      }
    }
  }
}

extern "C" void kernel_launch(void* const* d_in, const int* in_sizes, int n_in,
                              void* d_out, int out_size, void* d_ws, size_t ws_size,
                              hipStream_t stream) {
  (void)in_sizes; (void)n_in; (void)out_size; (void)ws_size;
  const float* x      = (const float*)d_in[0];
  const int*   ei     = (const int*)d_in[1];
  const int*   pairs  = (const int*)d_in[2];
  const float* W1     = (const float*)d_in[3];
  const float* a_src1 = (const float*)d_in[4];
  const float* a_dst1 = (const float*)d_in[5];
  const float* b1     = (const float*)d_in[6];
  const float* W2     = (const float*)d_in[7];
  const float* a_src2 = (const float*)d_in[8];
  const float* a_dst2 = (const float*)d_in[9];
  const float* b2     = (const float*)d_in[10];
  const float* Wp1    = (const float*)d_in[11];
  const float* bp1    = (const float*)d_in[12];
  const float* Wp2    = (const float*)d_in[13];
  const float* bp2    = (const float*)d_in[14];
  float* out = (float*)d_out;

  char* w = (char*)d_ws;
  auto alloc = [&](size_t bytes) -> void* {
    void* pp = (void*)w;
    w += (bytes + 255) & ~(size_t)255;
    return pp;
  };
  __half* h1h16 = (__half*)alloc((size_t)NN * 256 * 2);  // head-major [4][NN][64] fp16
  float*  AS1   = (float*)alloc((size_t)NN * 4 * 4);
  float*  AD1   = (float*)alloc((size_t)NN * 4 * 4);
  __half* h1a16 = (__half*)alloc((size_t)NN * 256 * 2);  // fp16 h1agg (gemm2 input)
  __half* h2h16 = (__half*)alloc((size_t)NN * 64 * 2);   // fp16 gather copy
  float*  AS2   = (float*)alloc((size_t)NN * 4);
  float*  AD2   = (float*)alloc((size_t)NN * 4);
  float*  h2agg = (float*)alloc((size_t)NN * 64 * 4);
  float*  AB    = (float*)alloc((size_t)NN * 128 * 4);
  f16*    W1T   = (f16*)alloc((size_t)256 * 256 * 2);    // fp16 W1 transposed [n][k]
  f16*    Wp2Th = (f16*)alloc((size_t)96 * 64 * 2);      // fp16 Wp2 transposed padded
  float*  bp2p  = (float*)alloc(96 * 4);
  f16*    W2T   = (f16*)alloc((size_t)64 * 256 * 2);     // fp16 W2 transposed [n][k]
  float*  w1    = (float*)alloc((size_t)4 * NEE * 4);    // edge weights layer 1
  float*  w2    = (float*)alloc((size_t)NEE * 4);        // edge weights layer 2
  int*    rp    = (int*)alloc((size_t)(NN + 1) * 4);
  int*    cnt   = (int*)alloc((size_t)NN * 4);
  int*    cur   = (int*)alloc((size_t)NN * 4);
  int*    col   = (int*)alloc((size_t)NEE * 4);

  (void)hipMemsetAsync(cnt, 0, (size_t)NN * 4, stream);
  (void)hipMemsetAsync(cur, 0, (size_t)NN * 4, stream);

  k_hist<<<NCHUNK * 8, 256, 0, stream>>>(ei, cnt);
  k_scan<<<1, 1024, 0, stream>>>(cnt, rp);
  k_scatter<<<NCHUNK * 8, 256, 0, stream>>>(ei, rp, cur, col);
  k_prep<<<256, 256, 0, stream>>>(Wp2, bp2, W2, W1, Wp2Th, bp2p, W2T, W1T);

  k_gemm1<<<NN / 16, 256, 0, stream>>>(x, W1T, a_src1, a_dst1, h1h16, AS1, AD1);
  k_edgew1<<<NN / 4, 256, 0, stream>>>(rp, col, AS1, AD1, w1);
  k_agg1<<<NN, 256, 0, stream>>>(rp, col, w1, h1h16, b1, h1a16);

  k_gemm2<<<NN / 16, 256, 0, stream>>>((const f16*)h1a16, W2T, a_src2, a_dst2, h2h16, AS2, AD2);
  k_edgew2<<<NN / 4, 256, 0, stream>>>(rp, col, AS2, AD2, w2);
  k_agg2<<<NN / 4, 256, 0, stream>>>(rp, col, w2, h2h16, b2, h2agg);

  k_predot<<<NN / 16, 128, 0, stream>>>(h2agg, Wp1, bp1, AB);
  k_pairs<<<NP / 64, 256, 0, stream>>>(pairs, AB, Wp2Th, bp2p, out);
}

// Round 24
// 255.098 us; speedup vs baseline: 1.0815x; 1.0709x over previous
//
#include <hip/hip_runtime.h>
#include <hip/hip_fp16.h>

#define NN 20000      // nodes
#define NE 640000     // edges (without self loops)
#define NEE 660000    // edges + self loops
#define NP 200000     // drug pairs
#define NEG 0.2f      // leaky relu slope
#define NPN 2500      // nodes per XCD pass (NN/8)

typedef _Float16 f16;
typedef __attribute__((ext_vector_type(4))) _Float16 f16x4;
typedef __attribute__((ext_vector_type(8))) _Float16 f16x8;
typedef __attribute__((ext_vector_type(4))) float f32x4;

#define ECHUNK 2048
#define NCHUNK ((NEE + ECHUNK - 1) / ECHUNK)   // 323

// ---------------- CSR build: XCD-pinned dst-region passes (round-23, proven) -------------
__global__ void k_hist(const int* __restrict__ ei, int* __restrict__ cnt) {
  int pass = blockIdx.x & 7;
  int chunk = blockIdx.x >> 3;
  int lo = pass * NPN, hi = lo + NPN;
  int base = chunk * ECHUNK;
#pragma unroll 1
  for (int k = 0; k < ECHUNK; k += 256) {
    int i = base + k + threadIdx.x;
    if (i >= NEE) break;
    int d = (i < NE) ? ei[NE + i] : (i - NE);
    if (d >= lo && d < hi) atomicAdd(&cnt[d], 1);
  }
}

__global__ __launch_bounds__(1024) void k_scan(const int* __restrict__ cnt, int* __restrict__ rp) {
  __shared__ int ps[1024];
  const int CH = 20;  // 1024*20 = 20480 >= 20000
  int t = threadIdx.x;
  int lo = t * CH, hi = lo + CH;
  if (hi > NN) hi = NN;
  if (lo > NN) lo = NN;
  int s = 0;
  for (int i = lo; i < hi; ++i) s += cnt[i];
  ps[t] = s;
  __syncthreads();
  for (int off = 1; off < 1024; off <<= 1) {
    int v = (t >= off) ? ps[t - off] : 0;
    __syncthreads();
    ps[t] += v;
    __syncthreads();
  }
  int run = (t > 0) ? ps[t - 1] : 0;
  for (int i = lo; i < hi; ++i) { rp[i] = run; run += cnt[i]; }
  if (t == 1023) rp[NN] = ps[1023];
}

__global__ void k_scatter(const int* __restrict__ ei, const int* __restrict__ rp,
                          int* __restrict__ cur, int* __restrict__ col) {
  int pass = blockIdx.x & 7;
  int chunk = blockIdx.x >> 3;
  int lo = pass * NPN, hi = lo + NPN;
  int base = chunk * ECHUNK;
#pragma unroll 1
  for (int k = 0; k < ECHUNK; k += 256) {
    int i = base + k + threadIdx.x;
    if (i >= NEE) break;
    int s, d;
    if (i < NE) { s = ei[i]; d = ei[NE + i]; } else { s = i - NE; d = s; }
    if (d >= lo && d < hi) {
      int pos = atomicAdd(&cur[d], 1);
      col[rp[d] + pos] = s;
    }
  }
}

// ---------------- prep: W1T, W2T, Wp2Th, bp2p, Wp1cT (concat-folded pair-MLP L1) ---------
__global__ void k_prep(const float* __restrict__ Wp2, const float* __restrict__ bp2,
                       const float* __restrict__ W2, const float* __restrict__ W1,
                       const float* __restrict__ Wp1,
                       f16* __restrict__ Wp2Th, float* __restrict__ bp2p,
                       f16* __restrict__ W2T, f16* __restrict__ W1T,
                       f16* __restrict__ Wp1cT) {
  int i = blockIdx.x * 256 + threadIdx.x;
  if (i < 96 * 64) {
    int o = i >> 6, t = i & 63;
    Wp2Th[o * 64 + t] = (o < 86) ? (f16)Wp2[t * 86 + o] : (f16)0.f;
  }
  if (i < 96) bp2p[i] = (i < 86) ? bp2[i] : 0.f;
  if (i < 64 * 256) {
    int n = i >> 8, k = i & 255;
    W2T[n * 256 + k] = (f16)W2[k * 64 + n];
  }
  if (i < 256 * 256) {
    int r = i >> 8, c = i & 255;
    W1T[c * 256 + r] = (f16)W1[i];
  }
  if (i < 128 * 64) {
    int c = i >> 6, k = i & 63;   // c: output col 0..127, k: h2a dim 0..63
    Wp1cT[c * 64 + k] = (c < 64) ? (f16)Wp1[k * 64 + c] : (f16)Wp1[(64 + k) * 64 + (c - 64)];
  }
}

// ---------------- GEMM1 v4 (MFMA): h1 = x @ W1, fp32 x staged+converted in-kernel --------
__global__ __launch_bounds__(256) void k_gemm1(
    const float* __restrict__ x, const f16* __restrict__ W1T,
    const float* __restrict__ as1, const float* __restrict__ ad1,
    __half* __restrict__ h1h16, float* __restrict__ AS1, float* __restrict__ AD1) {
  __shared__ f16 xs[16][264];     // 16 rows x 256 k, row stride 528B
  int tid = threadIdx.x;
  int base = blockIdx.x * 16;
  {
    int r = tid >> 4, ch = tid & 15;   // thread converts 16 floats (64B) of one row
    const float4* src = (const float4*)(x + (size_t)(base + r) * 256 + ch * 16);
    float4 a0 = src[0], a1 = src[1], a2 = src[2], a3 = src[3];
    f16 tmp[16];
    tmp[0] = (f16)a0.x; tmp[1] = (f16)a0.y; tmp[2] = (f16)a0.z; tmp[3] = (f16)a0.w;
    tmp[4] = (f16)a1.x; tmp[5] = (f16)a1.y; tmp[6] = (f16)a1.z; tmp[7] = (f16)a1.w;
    tmp[8] = (f16)a2.x; tmp[9] = (f16)a2.y; tmp[10] = (f16)a2.z; tmp[11] = (f16)a2.w;
    tmp[12] = (f16)a3.x; tmp[13] = (f16)a3.y; tmp[14] = (f16)a3.z; tmp[15] = (f16)a3.w;
    *(uint4*)&xs[r][ch * 16] = *(uint4*)&tmp[0];
    *(uint4*)&xs[r][ch * 16 + 8] = *(uint4*)&tmp[8];
  }
  __syncthreads();
  int wv = tid >> 6, lane = tid & 63;
  int head = wv;
  int lr = lane & 15, lk = lane >> 4;
  f32x4 acc[4] = {{0.f,0.f,0.f,0.f},{0.f,0.f,0.f,0.f},{0.f,0.f,0.f,0.f},{0.f,0.f,0.f,0.f}};
#pragma unroll
  for (int k0 = 0; k0 < 256; k0 += 32) {
    f16x8 a = *(const f16x8*)&xs[lr][k0 + lk * 8];
#pragma unroll
    for (int nt = 0; nt < 4; ++nt) {
      int n = head * 64 + nt * 16 + lr;
      f16x8 b = *(const f16x8*)(W1T + (size_t)n * 256 + k0 + lk * 8);
      acc[nt] = __builtin_amdgcn_mfma_f32_16x16x32_f16(a, b, acc[nt], 0, 0, 0);
    }
  }
#pragma unroll
  for (int nt = 0; nt < 4; ++nt) {
    int cc = nt * 16 + lr;
#pragma unroll
    for (int r = 0; r < 4; ++r) {
      int row = lk * 4 + r;
      h1h16[((size_t)head * NN + base + row) * 64 + cc] = __float2half(acc[nt][r]);
    }
  }
#pragma unroll
  for (int r = 0; r < 4; ++r) {
    float ps = 0.f, pd = 0.f;
#pragma unroll
    for (int nt = 0; nt < 4; ++nt) {
      int cc = nt * 16 + lr;
      ps += acc[nt][r] * as1[head * 64 + cc];
      pd += acc[nt][r] * ad1[head * 64 + cc];
    }
#pragma unroll
    for (int off = 1; off < 16; off <<= 1) {
      ps += __shfl_xor(ps, off);
      pd += __shfl_xor(pd, off);
    }
    if (lr == 0) {
      int n = base + lk * 4 + r;
      AS1[n * 4 + head] = ps;
      AD1[n * 4 + head] = pd;
    }
  }
}

// ---------------- GAT layer-1 agg v7: fused edge weights (round-21 system form) ----------
// Round-23 lesson: the edgew split was a system-level loss (w traffic + launches ate the
// local agg gain). Fused AS-gather+lrelu+exp inline, keeping fmaxf + fma_mix accumulate.
__global__ __launch_bounds__(256, 4) void k_agg1(
    const int* __restrict__ rp, const int* __restrict__ col,
    const float* __restrict__ AS1, const float* __restrict__ AD1,
    const __half* __restrict__ h1h16, const float* __restrict__ b1,
    __half* __restrict__ out16) {
  int b = blockIdx.x;
  int xcd = b & 7;
  int head = xcd >> 1;
  int grp = (b >> 3) * 2 + (xcd & 1);      // 0..4999, bijective per head
  int wave = threadIdx.x >> 6, lane = threadIdx.x & 63;
  int n = grp * 4 + wave;
  int g = lane >> 3, c8 = (lane & 7) * 8;  // edge group 0..7, col base (8 fp16 = 16B)
  int e0 = rp[n], e1 = rp[n + 1];
  const __half* hs = h1h16 + (size_t)head * NN * 64;
  float adv = AD1[n * 4 + head];
  float acc[8] = {0.f,0.f,0.f,0.f,0.f,0.f,0.f,0.f};
  float den = 0.f;

  int ee = e0 + g;
  bool v = ee < e1;
  int ec = v ? ee : e1 - 1;
  int s = col[ec];
  float asv = AS1[s * 4 + head];

  for (int e = e0; e < e1; e += 8) {
    int een = e + 8 + g;
    bool vn = een < e1;
    int ecn = vn ? een : e1 - 1;
    int sn = col[ecn];
    float asn = AS1[sn * 4 + head];
    float ev = asv + adv;
    ev = fmaxf(ev, NEG * ev);
    float p = v ? __expf(ev) : 0.f;
    float4 raw = *(const float4*)(hs + (size_t)s * 64 + c8);   // 16B = 8 fp16
    const f16* hf = (const f16*)&raw;
#pragma unroll
    for (int i = 0; i < 8; ++i) acc[i] += p * (float)hf[i];    // -> v_fma_mix_f32
    den += p;
    s = sn; asv = asn; v = vn;
  }
#pragma unroll
  for (int i = 0; i < 8; ++i) {
    acc[i] += __shfl_xor(acc[i], 8);
    acc[i] += __shfl_xor(acc[i], 16);
    acc[i] += __shfl_xor(acc[i], 32);
  }
  den += __shfl_xor(den, 8); den += __shfl_xor(den, 16); den += __shfl_xor(den, 32);
  if (lane < 8) {
    float inv = 1.f / den;
    int cbase = head * 64 + lane * 8;
    __half ho[8];
#pragma unroll
    for (int i = 0; i < 8; ++i) {
      float r = acc[i] * inv + b1[cbase + i];
      r = r > 0.f ? r : __expf(r) - 1.f;
      ho[i] = __float2half(r);
    }
    *(uint4*)(out16 + (size_t)n * 256 + cbase) = *(uint4*)&ho[0];
  }
}

// ---------------- GEMM2 v2 (MFMA): h2 = h1act @ W2 ----------------
__global__ __launch_bounds__(256) void k_gemm2(
    const f16* __restrict__ h1a16, const f16* __restrict__ W2T,
    const float* __restrict__ as2, const float* __restrict__ ad2,
    __half* __restrict__ h2h16, float* __restrict__ AS2, float* __restrict__ AD2) {
  __shared__ f16 xs[16][264];
  __shared__ float psL[4][16], pdL[4][16];
  int tid = threadIdx.x;
  int base = blockIdx.x * 16;
  {
    int r = tid >> 4, ch = tid & 15;
    const uint4* src = (const uint4*)(h1a16 + (size_t)(base + r) * 256 + ch * 16);
    uint4 v0 = src[0], v1 = src[1];
    *(uint4*)&xs[r][ch * 16] = v0;
    *(uint4*)&xs[r][ch * 16 + 8] = v1;
  }
  __syncthreads();
  int wv = tid >> 6, lane = tid & 63;
  int lr = lane & 15, lk = lane >> 4;
  f32x4 acc = {0.f, 0.f, 0.f, 0.f};
#pragma unroll
  for (int k0 = 0; k0 < 256; k0 += 32) {
    f16x8 a = *(const f16x8*)&xs[lr][k0 + lk * 8];
    f16x8 b = *(const f16x8*)(W2T + (size_t)(wv * 16 + lr) * 256 + k0 + lk * 8);
    acc = __builtin_amdgcn_mfma_f32_16x16x32_f16(a, b, acc, 0, 0, 0);
  }
  int cc = wv * 16 + lr;
  float asv = as2[cc], adv = ad2[cc];
  float psr[4], pdr[4];
#pragma unroll
  for (int r = 0; r < 4; ++r) {
    int row = lk * 4 + r;
    h2h16[(size_t)(base + row) * 64 + cc] = __float2half(acc[r]);
    float ps = acc[r] * asv, pd = acc[r] * adv;
#pragma unroll
    for (int off = 1; off < 16; off <<= 1) {
      ps += __shfl_xor(ps, off);
      pd += __shfl_xor(pd, off);
    }
    psr[r] = ps; pdr[r] = pd;
  }
  if (lr == 0) {
#pragma unroll
    for (int r = 0; r < 4; ++r) {
      psL[wv][lk * 4 + r] = psr[r];
      pdL[wv][lk * 4 + r] = pdr[r];
    }
  }
  __syncthreads();
  if (tid < 16) {
    AS2[base + tid] = psL[0][tid] + psL[1][tid] + psL[2][tid] + psL[3][tid];
    AD2[base + tid] = pdL[0][tid] + pdL[1][tid] + pdL[2][tid] + pdL[3][tid];
  }
}

// ---------------- GAT layer-2 agg v6: fused edge weights, fp16 out ----------------
// h2agg's only consumer is predot (now MFMA) -> emit fp16 directly.
__global__ __launch_bounds__(256, 4) void k_agg2(
    const int* __restrict__ rp, const int* __restrict__ col,
    const float* __restrict__ AS2, const float* __restrict__ AD2,
    const __half* __restrict__ h2h16, const float* __restrict__ b2,
    __half* __restrict__ out16) {
  int wave = threadIdx.x >> 6, lane = threadIdx.x & 63;
  int n = blockIdx.x * 4 + wave;
  int g = lane >> 3, c8 = (lane & 7) * 8;
  int e0 = rp[n], e1 = rp[n + 1];
  float adv = AD2[n];
  float acc[8] = {0.f,0.f,0.f,0.f,0.f,0.f,0.f,0.f};
  float den = 0.f;

  int ee = e0 + g;
  bool v = ee < e1;
  int ec = v ? ee : e1 - 1;
  int s = col[ec];
  float asv = AS2[s];

  for (int e = e0; e < e1; e += 8) {
    int een = e + 8 + g;
    bool vn = een < e1;
    int ecn = vn ? een : e1 - 1;
    int sn = col[ecn];
    float asn = AS2[sn];
    float ev = asv + adv;
    ev = fmaxf(ev, NEG * ev);
    float p = v ? __expf(ev) : 0.f;
    float4 raw = *(const float4*)(h2h16 + (size_t)s * 64 + c8);
    const f16* hf = (const f16*)&raw;
#pragma unroll
    for (int i = 0; i < 8; ++i) acc[i] += p * (float)hf[i];
    den += p;
    s = sn; asv = asn; v = vn;
  }
#pragma unroll
  for (int i = 0; i < 8; ++i) {
    acc[i] += __shfl_xor(acc[i], 8);
    acc[i] += __shfl_xor(acc[i], 16);
    acc[i] += __shfl_xor(acc[i], 32);
  }
  den += __shfl_xor(den, 8); den += __shfl_xor(den, 16); den += __shfl_xor(den, 32);
  if (lane < 8) {
    float inv = 1.f / den;
    int cbase = lane * 8;
    __half ho[8];
#pragma unroll
    for (int i = 0; i < 8; ++i) {
      float r = acc[i] * inv + b2[cbase + i];
      r = r > 0.f ? r : __expf(r) - 1.f;
      ho[i] = __float2half(r);
    }
    *(uint4*)(out16 + (size_t)n * 64 + cbase) = *(uint4*)&ho[0];
  }
}

// ---------------- predot v2 (MFMA): AB = h2a @ [Wp1_top|Wp1_bot] (+bp1 on cols<64) -------
// 16 rows/block, K=64, N=128. Wave wv owns n-tiles {2wv, 2wv+1}; 2 k-steps each = 4 MFMA.
__global__ __launch_bounds__(256) void k_predot(
    const f16* __restrict__ h2a16, const f16* __restrict__ Wp1cT,
    const float* __restrict__ bp1, float* __restrict__ AB) {
  __shared__ f16 xs[16][72];   // 16 rows x 64 k, row stride 144B (16B-aligned)
  int tid = threadIdx.x;
  int base = blockIdx.x * 16;
  {
    int r = tid >> 4, ch = tid & 15;   // thread stages 4 f16 (8B) of one row
    *(uint2*)&xs[r][ch * 4] = *(const uint2*)(h2a16 + (size_t)(base + r) * 64 + ch * 4);
  }
  __syncthreads();
  int wv = tid >> 6, lane = tid & 63;
  int lr = lane & 15, lk = lane >> 4;
#pragma unroll
  for (int t = 0; t < 2; ++t) {
    int nt = wv * 2 + t;                 // n-tile 0..7 (col block of 16)
    f32x4 acc = {0.f, 0.f, 0.f, 0.f};
#pragma unroll
    for (int k0 = 0; k0 < 64; k0 += 32) {
      f16x8 a = *(const f16x8*)&xs[lr][k0 + lk * 8];
      f16x8 b = *(const f16x8*)(Wp1cT + (size_t)(nt * 16 + lr) * 64 + k0 + lk * 8);
      acc = __builtin_amdgcn_mfma_f32_16x16x32_f16(a, b, acc, 0, 0, 0);
    }
    int c = nt * 16 + lr;                // output col 0..127
    float bb = (c < 64) ? bp1[c] : 0.f;
#pragma unroll
    for (int r = 0; r < 4; ++r) {
      int row = lk * 4 + r;
      AB[(size_t)(base + row) * 128 + c] = acc[r] + bb;
    }
  }
}

// ---------------- pair MLP v13: z-gather + MFMA layer 2 ----------------
__global__ __launch_bounds__(256) void k_pairs(
    const int* __restrict__ pairs, const float* __restrict__ AB,
    const f16* __restrict__ Wp2Th, const float* __restrict__ bp2p,
    float* __restrict__ out) {
  __shared__ f16 zh[64][72];  // [pair][t]
  int tid = threadIdx.x;
  int pp = tid & 63, q = tid >> 6;   // pair within block, z-quarter
  int p = blockIdx.x * 64 + pp;
  int pi = pairs[2 * p], pj = pairs[2 * p + 1];

  // ---- phase 1: z quarter q = relu(A[pi] + B[pj]) -> fp16 LDS  (bp1 folded in A)
  {
    const float4* ar = (const float4*)(AB + (size_t)pi * 128 + q * 16);
    const float4* br = (const float4*)(AB + (size_t)pj * 128 + 64 + q * 16);
    f16 zv[16];
#pragma unroll
    for (int m = 0; m < 4; ++m) {
      float4 a = ar[m], b = br[m];
      zv[m * 4]     = (f16)fmaxf(a.x + b.x, 0.f);
      zv[m * 4 + 1] = (f16)fmaxf(a.y + b.y, 0.f);
      zv[m * 4 + 2] = (f16)fmaxf(a.z + b.z, 0.f);
      zv[m * 4 + 3] = (f16)fmaxf(a.w + b.w, 0.f);
    }
    *(uint4*)&zh[pp][q * 16] = *(uint4*)&zv[0];
    *(uint4*)&zh[pp][q * 16 + 8] = *(uint4*)&zv[8];
  }
  __syncthreads();

  // ---- phase 2: out-tile = z @ Wp2 via MFMA; wave wv owns pairs wv*16..wv*16+15
  int wv = tid >> 6, lane = tid & 63;
  int lr = lane & 15, lk = lane >> 4;
#pragma unroll
  for (int nt = 0; nt < 6; ++nt) {
    f32x4 acc = {0.f, 0.f, 0.f, 0.f};
#pragma unroll
    for (int k0 = 0; k0 < 64; k0 += 32) {
      f16x8 a = *(const f16x8*)&zh[wv * 16 + lr][k0 + lk * 8];
      f16x8 b = *(const f16x8*)(Wp2Th + (size_t)(nt * 16 + lr) * 64 + k0 + lk * 8);
      acc = __builtin_amdgcn_mfma_f32_16x16x32_f16(a, b, acc, 0, 0, 0);
    }
    int o = nt * 16 + lr;
    if (o < 86) {
      float bb = bp2p[o];
#pragma unroll
      for (int r = 0; r < 4; ++r) {
        int pr = blockIdx.x * 64 + wv * 16 + lk * 4 + r;
        out[(size_t)pr * 86 + o] = acc[r] + bb;
      }
    }
  }
}

extern "C" void kernel_launch(void* const* d_in, const int* in_sizes, int n_in,
                              void* d_out, int out_size, void* d_ws, size_t ws_size,
                              hipStream_t stream) {
  (void)in_sizes; (void)n_in; (void)out_size; (void)ws_size;
  const float* x      = (const float*)d_in[0];
  const int*   ei     = (const int*)d_in[1];
  const int*   pairs  = (const int*)d_in[2];
  const float* W1     = (const float*)d_in[3];
  const float* a_src1 = (const float*)d_in[4];
  const float* a_dst1 = (const float*)d_in[5];
  const float* b1     = (const float*)d_in[6];
  const float* W2     = (const float*)d_in[7];
  const float* a_src2 = (const float*)d_in[8];
  const float* a_dst2 = (const float*)d_in[9];
  const float* b2     = (const float*)d_in[10];
  const float* Wp1    = (const float*)d_in[11];
  const float* bp1    = (const float*)d_in[12];
  const float* Wp2    = (const float*)d_in[13];
  const float* bp2    = (const float*)d_in[14];
  float* out = (float*)d_out;

  char* w = (char*)d_ws;
  auto alloc = [&](size_t bytes) -> void* {
    void* pp = (void*)w;
    w += (bytes + 255) & ~(size_t)255;
    return pp;
  };
  __half* h1h16 = (__half*)alloc((size_t)NN * 256 * 2);  // head-major [4][NN][64] fp16
  float*  AS1   = (float*)alloc((size_t)NN * 4 * 4);
  float*  AD1   = (float*)alloc((size_t)NN * 4 * 4);
  __half* h1a16 = (__half*)alloc((size_t)NN * 256 * 2);  // fp16 h1agg (gemm2 input)
  __half* h2h16 = (__half*)alloc((size_t)NN * 64 * 2);   // fp16 gather copy
  float*  AS2   = (float*)alloc((size_t)NN * 4);
  float*  AD2   = (float*)alloc((size_t)NN * 4);
  __half* h2a16 = (__half*)alloc((size_t)NN * 64 * 2);   // fp16 h2agg (predot input)
  float*  AB    = (float*)alloc((size_t)NN * 128 * 4);
  f16*    W1T   = (f16*)alloc((size_t)256 * 256 * 2);    // fp16 W1 transposed [n][k]
  f16*    Wp2Th = (f16*)alloc((size_t)96 * 64 * 2);      // fp16 Wp2 transposed padded
  float*  bp2p  = (float*)alloc(96 * 4);
  f16*    W2T   = (f16*)alloc((size_t)64 * 256 * 2);     // fp16 W2 transposed [n][k]
  f16*    Wp1cT = (f16*)alloc((size_t)128 * 64 * 2);     // fp16 concat-folded Wp1 [c][k]
  int*    rp    = (int*)alloc((size_t)(NN + 1) * 4);
  int*    cnt   = (int*)alloc((size_t)NN * 4);
  int*    cur   = (int*)alloc((size_t)NN * 4);
  int*    col   = (int*)alloc((size_t)NEE * 4);

  (void)hipMemsetAsync(cnt, 0, (size_t)NN * 4, stream);
  (void)hipMemsetAsync(cur, 0, (size_t)NN * 4, stream);

  k_hist<<<NCHUNK * 8, 256, 0, stream>>>(ei, cnt);
  k_scan<<<1, 1024, 0, stream>>>(cnt, rp);
  k_scatter<<<NCHUNK * 8, 256, 0, stream>>>(ei, rp, cur, col);
  k_prep<<<256, 256, 0, stream>>>(Wp2, bp2, W2, W1, Wp1, Wp2Th, bp2p, W2T, W1T, Wp1cT);

  k_gemm1<<<NN / 16, 256, 0, stream>>>(x, W1T, a_src1, a_dst1, h1h16, AS1, AD1);
  k_agg1<<<NN, 256, 0, stream>>>(rp, col, AS1, AD1, h1h16, b1, h1a16);

  k_gemm2<<<NN / 16, 256, 0, stream>>>((const f16*)h1a16, W2T, a_src2, a_dst2, h2h16, AS2, AD2);
  k_agg2<<<NN / 4, 256, 0, stream>>>(rp, col, AS2, AD2, h2h16, b2, h2a16);

  k_predot<<<NN / 16, 256, 0, stream>>>((const f16*)h2a16, Wp1cT, bp1, AB);
  k_pairs<<<NP / 64, 256, 0, stream>>>(pairs, AB, Wp2Th, bp2p, out);
}

// Round 25
// 247.227 us; speedup vs baseline: 1.1159x; 1.0318x over previous
//
#include <hip/hip_runtime.h>
#include <hip/hip_fp16.h>

#define NN 20000      // nodes
#define NE 640000     // edges (without self loops)
#define NEE 660000    // edges + self loops
#define NP 200000     // drug pairs
#define NEG 0.2f      // leaky relu slope
#define NPN 2500      // nodes per XCD pass (NN/8)

typedef _Float16 f16;
typedef __attribute__((ext_vector_type(4))) _Float16 f16x4;
typedef __attribute__((ext_vector_type(8))) _Float16 f16x8;
typedef __attribute__((ext_vector_type(4))) float f32x4;

#define ECHUNK 2048
#define NCHUNK ((NEE + ECHUNK - 1) / ECHUNK)   // 323

// ---------------- CSR build: XCD-pinned dst-region passes (round-23, proven) -------------
__global__ void k_hist(const int* __restrict__ ei, int* __restrict__ cnt) {
  int pass = blockIdx.x & 7;
  int chunk = blockIdx.x >> 3;
  int lo = pass * NPN, hi = lo + NPN;
  int base = chunk * ECHUNK;
#pragma unroll 1
  for (int k = 0; k < ECHUNK; k += 256) {
    int i = base + k + threadIdx.x;
    if (i >= NEE) break;
    int d = (i < NE) ? ei[NE + i] : (i - NE);
    if (d >= lo && d < hi) atomicAdd(&cnt[d], 1);
  }
}

__global__ __launch_bounds__(1024) void k_scan(const int* __restrict__ cnt, int* __restrict__ rp) {
  __shared__ int ps[1024];
  const int CH = 20;  // 1024*20 = 20480 >= 20000
  int t = threadIdx.x;
  int lo = t * CH, hi = lo + CH;
  if (hi > NN) hi = NN;
  if (lo > NN) lo = NN;
  int s = 0;
  for (int i = lo; i < hi; ++i) s += cnt[i];
  ps[t] = s;
  __syncthreads();
  for (int off = 1; off < 1024; off <<= 1) {
    int v = (t >= off) ? ps[t - off] : 0;
    __syncthreads();
    ps[t] += v;
    __syncthreads();
  }
  int run = (t > 0) ? ps[t - 1] : 0;
  for (int i = lo; i < hi; ++i) { rp[i] = run; run += cnt[i]; }
  if (t == 1023) rp[NN] = ps[1023];
}

__global__ void k_scatter(const int* __restrict__ ei, const int* __restrict__ rp,
                          int* __restrict__ cur, int* __restrict__ col) {
  int pass = blockIdx.x & 7;
  int chunk = blockIdx.x >> 3;
  int lo = pass * NPN, hi = lo + NPN;
  int base = chunk * ECHUNK;
#pragma unroll 1
  for (int k = 0; k < ECHUNK; k += 256) {
    int i = base + k + threadIdx.x;
    if (i >= NEE) break;
    int s, d;
    if (i < NE) { s = ei[i]; d = ei[NE + i]; } else { s = i - NE; d = s; }
    if (d >= lo && d < hi) {
      int pos = atomicAdd(&cur[d], 1);
      col[rp[d] + pos] = s;
    }
  }
}

// ---------------- prep: W1T, W2T, Wp2Th, bp2p, Wp1cT (concat-folded pair-MLP L1) ---------
__global__ void k_prep(const float* __restrict__ Wp2, const float* __restrict__ bp2,
                       const float* __restrict__ W2, const float* __restrict__ W1,
                       const float* __restrict__ Wp1,
                       f16* __restrict__ Wp2Th, float* __restrict__ bp2p,
                       f16* __restrict__ W2T, f16* __restrict__ W1T,
                       f16* __restrict__ Wp1cT) {
  int i = blockIdx.x * 256 + threadIdx.x;
  if (i < 96 * 64) {
    int o = i >> 6, t = i & 63;
    Wp2Th[o * 64 + t] = (o < 86) ? (f16)Wp2[t * 86 + o] : (f16)0.f;
  }
  if (i < 96) bp2p[i] = (i < 86) ? bp2[i] : 0.f;
  if (i < 64 * 256) {
    int n = i >> 8, k = i & 255;
    W2T[n * 256 + k] = (f16)W2[k * 64 + n];
  }
  if (i < 256 * 256) {
    int r = i >> 8, c = i & 255;
    W1T[c * 256 + r] = (f16)W1[i];
  }
  if (i < 128 * 64) {
    int c = i >> 6, k = i & 63;   // c: output col 0..127, k: h2a dim 0..63
    Wp1cT[c * 64 + k] = (c < 64) ? (f16)Wp1[k * 64 + c] : (f16)Wp1[(64 + k) * 64 + (c - 64)];
  }
}

// ---------------- GEMM1 v4 (MFMA): h1 = x @ W1, fp32 x staged+converted in-kernel --------
__global__ __launch_bounds__(256) void k_gemm1(
    const float* __restrict__ x, const f16* __restrict__ W1T,
    const float* __restrict__ as1, const float* __restrict__ ad1,
    __half* __restrict__ h1h16, float* __restrict__ AS1, float* __restrict__ AD1) {
  __shared__ f16 xs[16][264];     // 16 rows x 256 k, row stride 528B
  int tid = threadIdx.x;
  int base = blockIdx.x * 16;
  {
    int r = tid >> 4, ch = tid & 15;   // thread converts 16 floats (64B) of one row
    const float4* src = (const float4*)(x + (size_t)(base + r) * 256 + ch * 16);
    float4 a0 = src[0], a1 = src[1], a2 = src[2], a3 = src[3];
    f16 tmp[16];
    tmp[0] = (f16)a0.x; tmp[1] = (f16)a0.y; tmp[2] = (f16)a0.z; tmp[3] = (f16)a0.w;
    tmp[4] = (f16)a1.x; tmp[5] = (f16)a1.y; tmp[6] = (f16)a1.z; tmp[7] = (f16)a1.w;
    tmp[8] = (f16)a2.x; tmp[9] = (f16)a2.y; tmp[10] = (f16)a2.z; tmp[11] = (f16)a2.w;
    tmp[12] = (f16)a3.x; tmp[13] = (f16)a3.y; tmp[14] = (f16)a3.z; tmp[15] = (f16)a3.w;
    *(uint4*)&xs[r][ch * 16] = *(uint4*)&tmp[0];
    *(uint4*)&xs[r][ch * 16 + 8] = *(uint4*)&tmp[8];
  }
  __syncthreads();
  int wv = tid >> 6, lane = tid & 63;
  int head = wv;
  int lr = lane & 15, lk = lane >> 4;
  f32x4 acc[4] = {{0.f,0.f,0.f,0.f},{0.f,0.f,0.f,0.f},{0.f,0.f,0.f,0.f},{0.f,0.f,0.f,0.f}};
#pragma unroll
  for (int k0 = 0; k0 < 256; k0 += 32) {
    f16x8 a = *(const f16x8*)&xs[lr][k0 + lk * 8];
#pragma unroll
    for (int nt = 0; nt < 4; ++nt) {
      int n = head * 64 + nt * 16 + lr;
      f16x8 b = *(const f16x8*)(W1T + (size_t)n * 256 + k0 + lk * 8);
      acc[nt] = __builtin_amdgcn_mfma_f32_16x16x32_f16(a, b, acc[nt], 0, 0, 0);
    }
  }
#pragma unroll
  for (int nt = 0; nt < 4; ++nt) {
    int cc = nt * 16 + lr;
#pragma unroll
    for (int r = 0; r < 4; ++r) {
      int row = lk * 4 + r;
      h1h16[((size_t)head * NN + base + row) * 64 + cc] = __float2half(acc[nt][r]);
    }
  }
#pragma unroll
  for (int r = 0; r < 4; ++r) {
    float ps = 0.f, pd = 0.f;
#pragma unroll
    for (int nt = 0; nt < 4; ++nt) {
      int cc = nt * 16 + lr;
      ps += acc[nt][r] * as1[head * 64 + cc];
      pd += acc[nt][r] * ad1[head * 64 + cc];
    }
#pragma unroll
    for (int off = 1; off < 16; off <<= 1) {
      ps += __shfl_xor(ps, off);
      pd += __shfl_xor(pd, off);
    }
    if (lr == 0) {
      int n = base + lk * 4 + r;
      AS1[n * 4 + head] = ps;
      AD1[n * 4 + head] = pd;
    }
  }
}

// ---------------- GAT layer-1 agg v8: depth-2 payload pipeline ----------------
// Round-24 diagnosis: per-SIMD VALU util ~25% -> LATENCY-bound. The h-row gather was
// issued in-iteration and consumed immediately (full L2 latency exposed every iter).
// Now: col prefetched 2 iters ahead; AS1 + h-gather issued 1 iter ahead -> iteration i
// computes on registers loaded at i-1 while i+1's gather is in flight.
__global__ __launch_bounds__(256, 4) void k_agg1(
    const int* __restrict__ rp, const int* __restrict__ col,
    const float* __restrict__ AS1, const float* __restrict__ AD1,
    const __half* __restrict__ h1h16, const float* __restrict__ b1,
    __half* __restrict__ out16) {
  int b = blockIdx.x;
  int xcd = b & 7;
  int head = xcd >> 1;
  int grp = (b >> 3) * 2 + (xcd & 1);      // 0..4999, bijective per head
  int wave = threadIdx.x >> 6, lane = threadIdx.x & 63;
  int n = grp * 4 + wave;
  int g = lane >> 3, c8 = (lane & 7) * 8;  // edge group 0..7, col base (8 fp16 = 16B)
  int e0 = rp[n], e1 = rp[n + 1];
  const __half* hs = h1h16 + (size_t)head * NN * 64;
  float adv = AD1[n * 4 + head];
  float acc[8] = {0.f,0.f,0.f,0.f,0.f,0.f,0.f,0.f};
  float den = 0.f;

  // pipeline prologue: iter0 fully loaded (s,as,raw); iter1 index loaded
  int ee = e0 + g;
  bool vA = ee < e1;
  int ecA = vA ? ee : e1 - 1;
  int sA = col[ecA];
  float asA = AS1[sA * 4 + head];
  float4 rawA = *(const float4*)(hs + (size_t)sA * 64 + c8);

  int eeB = e0 + 8 + g;
  bool vB = eeB < e1;
  int ecB = vB ? eeB : e1 - 1;
  int sB = col[ecB];

  for (int e = e0; e < e1; e += 8) {
    // issue iter i+1 payload (sB known) and iter i+2 index
    float asB = AS1[sB * 4 + head];
    float4 rawB = *(const float4*)(hs + (size_t)sB * 64 + c8);
    int eeC = e + 16 + g;
    bool vC = eeC < e1;
    int ecC = vC ? eeC : e1 - 1;
    int sC = col[ecC];
    // compute iter i on in-register values
    float ev = asA + adv;
    ev = fmaxf(ev, NEG * ev);
    float p = vA ? __expf(ev) : 0.f;
    const f16* hf = (const f16*)&rawA;
#pragma unroll
    for (int i = 0; i < 8; ++i) acc[i] += p * (float)hf[i];    // -> v_fma_mix_f32
    den += p;
    // rotate pipeline
    sA = sB; asA = asB; rawA = rawB; vA = vB;
    sB = sC; vB = vC;
  }
#pragma unroll
  for (int i = 0; i < 8; ++i) {
    acc[i] += __shfl_xor(acc[i], 8);
    acc[i] += __shfl_xor(acc[i], 16);
    acc[i] += __shfl_xor(acc[i], 32);
  }
  den += __shfl_xor(den, 8); den += __shfl_xor(den, 16); den += __shfl_xor(den, 32);
  if (lane < 8) {
    float inv = 1.f / den;
    int cbase = head * 64 + lane * 8;
    __half ho[8];
#pragma unroll
    for (int i = 0; i < 8; ++i) {
      float r = acc[i] * inv + b1[cbase + i];
      r = r > 0.f ? r : __expf(r) - 1.f;
      ho[i] = __float2half(r);
    }
    *(uint4*)(out16 + (size_t)n * 256 + cbase) = *(uint4*)&ho[0];
  }
}

// ---------------- GEMM2 v2 (MFMA): h2 = h1act @ W2 ----------------
__global__ __launch_bounds__(256) void k_gemm2(
    const f16* __restrict__ h1a16, const f16* __restrict__ W2T,
    const float* __restrict__ as2, const float* __restrict__ ad2,
    __half* __restrict__ h2h16, float* __restrict__ AS2, float* __restrict__ AD2) {
  __shared__ f16 xs[16][264];
  __shared__ float psL[4][16], pdL[4][16];
  int tid = threadIdx.x;
  int base = blockIdx.x * 16;
  {
    int r = tid >> 4, ch = tid & 15;
    const uint4* src = (const uint4*)(h1a16 + (size_t)(base + r) * 256 + ch * 16);
    uint4 v0 = src[0], v1 = src[1];
    *(uint4*)&xs[r][ch * 16] = v0;
    *(uint4*)&xs[r][ch * 16 + 8] = v1;
  }
  __syncthreads();
  int wv = tid >> 6, lane = tid & 63;
  int lr = lane & 15, lk = lane >> 4;
  f32x4 acc = {0.f, 0.f, 0.f, 0.f};
#pragma unroll
  for (int k0 = 0; k0 < 256; k0 += 32) {
    f16x8 a = *(const f16x8*)&xs[lr][k0 + lk * 8];
    f16x8 b = *(const f16x8*)(W2T + (size_t)(wv * 16 + lr) * 256 + k0 + lk * 8);
    acc = __builtin_amdgcn_mfma_f32_16x16x32_f16(a, b, acc, 0, 0, 0);
  }
  int cc = wv * 16 + lr;
  float asv = as2[cc], adv = ad2[cc];
  float psr[4], pdr[4];
#pragma unroll
  for (int r = 0; r < 4; ++r) {
    int row = lk * 4 + r;
    h2h16[(size_t)(base + row) * 64 + cc] = __float2half(acc[r]);
    float ps = acc[r] * asv, pd = acc[r] * adv;
#pragma unroll
    for (int off = 1; off < 16; off <<= 1) {
      ps += __shfl_xor(ps, off);
      pd += __shfl_xor(pd, off);
    }
    psr[r] = ps; pdr[r] = pd;
  }
  if (lr == 0) {
#pragma unroll
    for (int r = 0; r < 4; ++r) {
      psL[wv][lk * 4 + r] = psr[r];
      pdL[wv][lk * 4 + r] = pdr[r];
    }
  }
  __syncthreads();
  if (tid < 16) {
    AS2[base + tid] = psL[0][tid] + psL[1][tid] + psL[2][tid] + psL[3][tid];
    AD2[base + tid] = pdL[0][tid] + pdL[1][tid] + pdL[2][tid] + pdL[3][tid];
  }
}

// ---------------- GAT layer-2 agg v7: depth-2 payload pipeline, fp16 out ----------------
__global__ __launch_bounds__(256, 4) void k_agg2(
    const int* __restrict__ rp, const int* __restrict__ col,
    const float* __restrict__ AS2, const float* __restrict__ AD2,
    const __half* __restrict__ h2h16, const float* __restrict__ b2,
    __half* __restrict__ out16) {
  int wave = threadIdx.x >> 6, lane = threadIdx.x & 63;
  int n = blockIdx.x * 4 + wave;
  int g = lane >> 3, c8 = (lane & 7) * 8;
  int e0 = rp[n], e1 = rp[n + 1];
  float adv = AD2[n];
  float acc[8] = {0.f,0.f,0.f,0.f,0.f,0.f,0.f,0.f};
  float den = 0.f;

  int ee = e0 + g;
  bool vA = ee < e1;
  int ecA = vA ? ee : e1 - 1;
  int sA = col[ecA];
  float asA = AS2[sA];
  float4 rawA = *(const float4*)(h2h16 + (size_t)sA * 64 + c8);

  int eeB = e0 + 8 + g;
  bool vB = eeB < e1;
  int ecB = vB ? eeB : e1 - 1;
  int sB = col[ecB];

  for (int e = e0; e < e1; e += 8) {
    float asB = AS2[sB];
    float4 rawB = *(const float4*)(h2h16 + (size_t)sB * 64 + c8);
    int eeC = e + 16 + g;
    bool vC = eeC < e1;
    int ecC = vC ? eeC : e1 - 1;
    int sC = col[ecC];
    float ev = asA + adv;
    ev = fmaxf(ev, NEG * ev);
    float p = vA ? __expf(ev) : 0.f;
    const f16* hf = (const f16*)&rawA;
#pragma unroll
    for (int i = 0; i < 8; ++i) acc[i] += p * (float)hf[i];
    den += p;
    sA = sB; asA = asB; rawA = rawB; vA = vB;
    sB = sC; vB = vC;
  }
#pragma unroll
  for (int i = 0; i < 8; ++i) {
    acc[i] += __shfl_xor(acc[i], 8);
    acc[i] += __shfl_xor(acc[i], 16);
    acc[i] += __shfl_xor(acc[i], 32);
  }
  den += __shfl_xor(den, 8); den += __shfl_xor(den, 16); den += __shfl_xor(den, 32);
  if (lane < 8) {
    float inv = 1.f / den;
    int cbase = lane * 8;
    __half ho[8];
#pragma unroll
    for (int i = 0; i < 8; ++i) {
      float r = acc[i] * inv + b2[cbase + i];
      r = r > 0.f ? r : __expf(r) - 1.f;
      ho[i] = __float2half(r);
    }
    *(uint4*)(out16 + (size_t)n * 64 + cbase) = *(uint4*)&ho[0];
  }
}

// ---------------- predot v2 (MFMA): AB = h2a @ [Wp1_top|Wp1_bot] (+bp1 on cols<64) -------
__global__ __launch_bounds__(256) void k_predot(
    const f16* __restrict__ h2a16, const f16* __restrict__ Wp1cT,
    const float* __restrict__ bp1, float* __restrict__ AB) {
  __shared__ f16 xs[16][72];   // 16 rows x 64 k, row stride 144B (16B-aligned)
  int tid = threadIdx.x;
  int base = blockIdx.x * 16;
  {
    int r = tid >> 4, ch = tid & 15;   // thread stages 4 f16 (8B) of one row
    *(uint2*)&xs[r][ch * 4] = *(const uint2*)(h2a16 + (size_t)(base + r) * 64 + ch * 4);
  }
  __syncthreads();
  int wv = tid >> 6, lane = tid & 63;
  int lr = lane & 15, lk = lane >> 4;
#pragma unroll
  for (int t = 0; t < 2; ++t) {
    int nt = wv * 2 + t;                 // n-tile 0..7 (col block of 16)
    f32x4 acc = {0.f, 0.f, 0.f, 0.f};
#pragma unroll
    for (int k0 = 0; k0 < 64; k0 += 32) {
      f16x8 a = *(const f16x8*)&xs[lr][k0 + lk * 8];
      f16x8 b = *(const f16x8*)(Wp1cT + (size_t)(nt * 16 + lr) * 64 + k0 + lk * 8);
      acc = __builtin_amdgcn_mfma_f32_16x16x32_f16(a, b, acc, 0, 0, 0);
    }
    int c = nt * 16 + lr;                // output col 0..127
    float bb = (c < 64) ? bp1[c] : 0.f;
#pragma unroll
    for (int r = 0; r < 4; ++r) {
      int row = lk * 4 + r;
      AB[(size_t)(base + row) * 128 + c] = acc[r] + bb;
    }
  }
}

// ---------------- pair MLP v13: z-gather + MFMA layer 2 ----------------
__global__ __launch_bounds__(256) void k_pairs(
    const int* __restrict__ pairs, const float* __restrict__ AB,
    const f16* __restrict__ Wp2Th, const float* __restrict__ bp2p,
    float* __restrict__ out) {
  __shared__ f16 zh[64][72];  // [pair][t]
  int tid = threadIdx.x;
  int pp = tid & 63, q = tid >> 6;   // pair within block, z-quarter
  int p = blockIdx.x * 64 + pp;
  int pi = pairs[2 * p], pj = pairs[2 * p + 1];

  // ---- phase 1: z quarter q = relu(A[pi] + B[pj]) -> fp16 LDS  (bp1 folded in A)
  {
    const float4* ar = (const float4*)(AB + (size_t)pi * 128 + q * 16);
    const float4* br = (const float4*)(AB + (size_t)pj * 128 + 64 + q * 16);
    f16 zv[16];
#pragma unroll
    for (int m = 0; m < 4; ++m) {
      float4 a = ar[m], b = br[m];
      zv[m * 4]     = (f16)fmaxf(a.x + b.x, 0.f);
      zv[m * 4 + 1] = (f16)fmaxf(a.y + b.y, 0.f);
      zv[m * 4 + 2] = (f16)fmaxf(a.z + b.z, 0.f);
      zv[m * 4 + 3] = (f16)fmaxf(a.w + b.w, 0.f);
    }
    *(uint4*)&zh[pp][q * 16] = *(uint4*)&zv[0];
    *(uint4*)&zh[pp][q * 16 + 8] = *(uint4*)&zv[8];
  }
  __syncthreads();

  // ---- phase 2: out-tile = z @ Wp2 via MFMA; wave wv owns pairs wv*16..wv*16+15
  int wv = tid >> 6, lane = tid & 63;
  int lr = lane & 15, lk = lane >> 4;
#pragma unroll
  for (int nt = 0; nt < 6; ++nt) {
    f32x4 acc = {0.f, 0.f, 0.f, 0.f};
#pragma unroll
    for (int k0 = 0; k0 < 64; k0 += 32) {
      f16x8 a = *(const f16x8*)&zh[wv * 16 + lr][k0 + lk * 8];
      f16x8 b = *(const f16x8*)(Wp2Th + (size_t)(nt * 16 + lr) * 64 + k0 + lk * 8);
      acc = __builtin_amdgcn_mfma_f32_16x16x32_f16(a, b, acc, 0, 0, 0);
    }
    int o = nt * 16 + lr;
    if (o < 86) {
      float bb = bp2p[o];
#pragma unroll
      for (int r = 0; r < 4; ++r) {
        int pr = blockIdx.x * 64 + wv * 16 + lk * 4 + r;
        out[(size_t)pr * 86 + o] = acc[r] + bb;
      }
    }
  }
}

extern "C" void kernel_launch(void* const* d_in, const int* in_sizes, int n_in,
                              void* d_out, int out_size, void* d_ws, size_t ws_size,
                              hipStream_t stream) {
  (void)in_sizes; (void)n_in; (void)out_size; (void)ws_size;
  const float* x      = (const float*)d_in[0];
  const int*   ei     = (const int*)d_in[1];
  const int*   pairs  = (const int*)d_in[2];
  const float* W1     = (const float*)d_in[3];
  const float* a_src1 = (const float*)d_in[4];
  const float* a_dst1 = (const float*)d_in[5];
  const float* b1     = (const float*)d_in[6];
  const float* W2     = (const float*)d_in[7];
  const float* a_src2 = (const float*)d_in[8];
  const float* a_dst2 = (const float*)d_in[9];
  const float* b2     = (const float*)d_in[10];
  const float* Wp1    = (const float*)d_in[11];
  const float* bp1    = (const float*)d_in[12];
  const float* Wp2    = (const float*)d_in[13];
  const float* bp2    = (const float*)d_in[14];
  float* out = (float*)d_out;

  char* w = (char*)d_ws;
  auto alloc = [&](size_t bytes) -> void* {
    void* pp = (void*)w;
    w += (bytes + 255) & ~(size_t)255;
    return pp;
  };
  __half* h1h16 = (__half*)alloc((size_t)NN * 256 * 2);  // head-major [4][NN][64] fp16
  float*  AS1   = (float*)alloc((size_t)NN * 4 * 4);
  float*  AD1   = (float*)alloc((size_t)NN * 4 * 4);
  __half* h1a16 = (__half*)alloc((size_t)NN * 256 * 2);  // fp16 h1agg (gemm2 input)
  __half* h2h16 = (__half*)alloc((size_t)NN * 64 * 2);   // fp16 gather copy
  float*  AS2   = (float*)alloc((size_t)NN * 4);
  float*  AD2   = (float*)alloc((size_t)NN * 4);
  __half* h2a16 = (__half*)alloc((size_t)NN * 64 * 2);   // fp16 h2agg (predot input)
  float*  AB    = (float*)alloc((size_t)NN * 128 * 4);
  f16*    W1T   = (f16*)alloc((size_t)256 * 256 * 2);    // fp16 W1 transposed [n][k]
  f16*    Wp2Th = (f16*)alloc((size_t)96 * 64 * 2);      // fp16 Wp2 transposed padded
  float*  bp2p  = (float*)alloc(96 * 4);
  f16*    W2T   = (f16*)alloc((size_t)64 * 256 * 2);     // fp16 W2 transposed [n][k]
  f16*    Wp1cT = (f16*)alloc((size_t)128 * 64 * 2);     // fp16 concat-folded Wp1 [c][k]
  int*    rp    = (int*)alloc((size_t)(NN + 1) * 4);
  int*    cnt   = (int*)alloc((size_t)NN * 4);
  int*    cur   = (int*)alloc((size_t)NN * 4);
  int*    col   = (int*)alloc((size_t)NEE * 4);

  (void)hipMemsetAsync(cnt, 0, (size_t)NN * 4, stream);
  (void)hipMemsetAsync(cur, 0, (size_t)NN * 4, stream);

  k_hist<<<NCHUNK * 8, 256, 0, stream>>>(ei, cnt);
  k_scan<<<1, 1024, 0, stream>>>(cnt, rp);
  k_scatter<<<NCHUNK * 8, 256, 0, stream>>>(ei, rp, cur, col);
  k_prep<<<256, 256, 0, stream>>>(Wp2, bp2, W2, W1, Wp1, Wp2Th, bp2p, W2T, W1T, Wp1cT);

  k_gemm1<<<NN / 16, 256, 0, stream>>>(x, W1T, a_src1, a_dst1, h1h16, AS1, AD1);
  k_agg1<<<NN, 256, 0, stream>>>(rp, col, AS1, AD1, h1h16, b1, h1a16);

  k_gemm2<<<NN / 16, 256, 0, stream>>>((const f16*)h1a16, W2T, a_src2, a_dst2, h2h16, AS2, AD2);
  k_agg2<<<NN / 4, 256, 0, stream>>>(rp, col, AS2, AD2, h2h16, b2, h2a16);

  k_predot<<<NN / 16, 256, 0, stream>>>((const f16*)h2a16, Wp1cT, bp1, AB);
  k_pairs<<<NP / 64, 256, 0, stream>>>(pairs, AB, Wp2Th, bp2p, out);
}

// Round 26
// 236.767 us; speedup vs baseline: 1.1652x; 1.0442x over previous
//
#include <hip/hip_runtime.h>
#include <hip/hip_fp16.h>

#define NN 20000      // nodes
#define NE 640000     // edges (without self loops)
#define NEE 660000    // edges + self loops
#define NP 200000     // drug pairs
#define NEG 0.2f      // leaky relu slope
#define NPN 2500      // nodes per XCD pass (NN/8)

typedef _Float16 f16;
typedef __attribute__((ext_vector_type(4))) _Float16 f16x4;
typedef __attribute__((ext_vector_type(8))) _Float16 f16x8;
typedef __attribute__((ext_vector_type(4))) float f32x4;

#define ECHUNK 2048
#define NCHUNK ((NEE + ECHUNK - 1) / ECHUNK)   // 323

// ---------------- CSR build: XCD-pinned dst-region passes (round-23, proven) -------------
__global__ void k_hist(const int* __restrict__ ei, int* __restrict__ cnt) {
  int pass = blockIdx.x & 7;
  int chunk = blockIdx.x >> 3;
  int lo = pass * NPN, hi = lo + NPN;
  int base = chunk * ECHUNK;
#pragma unroll 1
  for (int k = 0; k < ECHUNK; k += 256) {
    int i = base + k + threadIdx.x;
    if (i >= NEE) break;
    int d = (i < NE) ? ei[NE + i] : (i - NE);
    if (d >= lo && d < hi) atomicAdd(&cnt[d], 1);
  }
}

__global__ __launch_bounds__(1024) void k_scan(const int* __restrict__ cnt, int* __restrict__ rp) {
  __shared__ int ps[1024];
  const int CH = 20;  // 1024*20 = 20480 >= 20000
  int t = threadIdx.x;
  int lo = t * CH, hi = lo + CH;
  if (hi > NN) hi = NN;
  if (lo > NN) lo = NN;
  int s = 0;
  for (int i = lo; i < hi; ++i) s += cnt[i];
  ps[t] = s;
  __syncthreads();
  for (int off = 1; off < 1024; off <<= 1) {
    int v = (t >= off) ? ps[t - off] : 0;
    __syncthreads();
    ps[t] += v;
    __syncthreads();
  }
  int run = (t > 0) ? ps[t - 1] : 0;
  for (int i = lo; i < hi; ++i) { rp[i] = run; run += cnt[i]; }
  if (t == 1023) rp[NN] = ps[1023];
}

__global__ void k_scatter(const int* __restrict__ ei, const int* __restrict__ rp,
                          int* __restrict__ cur, int* __restrict__ col) {
  int pass = blockIdx.x & 7;
  int chunk = blockIdx.x >> 3;
  int lo = pass * NPN, hi = lo + NPN;
  int base = chunk * ECHUNK;
#pragma unroll 1
  for (int k = 0; k < ECHUNK; k += 256) {
    int i = base + k + threadIdx.x;
    if (i >= NEE) break;
    int s, d;
    if (i < NE) { s = ei[i]; d = ei[NE + i]; } else { s = i - NE; d = s; }
    if (d >= lo && d < hi) {
      int pos = atomicAdd(&cur[d], 1);
      col[rp[d] + pos] = s;
    }
  }
}

// ---------------- prep: W1T, W2T, Wp2Th, bp2p, Wp1cT (concat-folded pair-MLP L1) ---------
__global__ void k_prep(const float* __restrict__ Wp2, const float* __restrict__ bp2,
                       const float* __restrict__ W2, const float* __restrict__ W1,
                       const float* __restrict__ Wp1,
                       f16* __restrict__ Wp2Th, float* __restrict__ bp2p,
                       f16* __restrict__ W2T, f16* __restrict__ W1T,
                       f16* __restrict__ Wp1cT) {
  int i = blockIdx.x * 256 + threadIdx.x;
  if (i < 96 * 64) {
    int o = i >> 6, t = i & 63;
    Wp2Th[o * 64 + t] = (o < 86) ? (f16)Wp2[t * 86 + o] : (f16)0.f;
  }
  if (i < 96) bp2p[i] = (i < 86) ? bp2[i] : 0.f;
  if (i < 64 * 256) {
    int n = i >> 8, k = i & 255;
    W2T[n * 256 + k] = (f16)W2[k * 64 + n];
  }
  if (i < 256 * 256) {
    int r = i >> 8, c = i & 255;
    W1T[c * 256 + r] = (f16)W1[i];
  }
  if (i < 128 * 64) {
    int c = i >> 6, k = i & 63;   // c: output col 0..127, k: h2a dim 0..63
    Wp1cT[c * 64 + k] = (c < 64) ? (f16)Wp1[k * 64 + c] : (f16)Wp1[(64 + k) * 64 + (c - 64)];
  }
}

// ---------------- GEMM1 v4 (MFMA): h1 = x @ W1, fp32 x staged+converted in-kernel --------
__global__ __launch_bounds__(256) void k_gemm1(
    const float* __restrict__ x, const f16* __restrict__ W1T,
    const float* __restrict__ as1, const float* __restrict__ ad1,
    __half* __restrict__ h1h16, float* __restrict__ AS1, float* __restrict__ AD1) {
  __shared__ f16 xs[16][264];     // 16 rows x 256 k, row stride 528B
  int tid = threadIdx.x;
  int base = blockIdx.x * 16;
  {
    int r = tid >> 4, ch = tid & 15;   // thread converts 16 floats (64B) of one row
    const float4* src = (const float4*)(x + (size_t)(base + r) * 256 + ch * 16);
    float4 a0 = src[0], a1 = src[1], a2 = src[2], a3 = src[3];
    f16 tmp[16];
    tmp[0] = (f16)a0.x; tmp[1] = (f16)a0.y; tmp[2] = (f16)a0.z; tmp[3] = (f16)a0.w;
    tmp[4] = (f16)a1.x; tmp[5] = (f16)a1.y; tmp[6] = (f16)a1.z; tmp[7] = (f16)a1.w;
    tmp[8] = (f16)a2.x; tmp[9] = (f16)a2.y; tmp[10] = (f16)a2.z; tmp[11] = (f16)a2.w;
    tmp[12] = (f16)a3.x; tmp[13] = (f16)a3.y; tmp[14] = (f16)a3.z; tmp[15] = (f16)a3.w;
    *(uint4*)&xs[r][ch * 16] = *(uint4*)&tmp[0];
    *(uint4*)&xs[r][ch * 16 + 8] = *(uint4*)&tmp[8];
  }
  __syncthreads();
  int wv = tid >> 6, lane = tid & 63;
  int head = wv;
  int lr = lane & 15, lk = lane >> 4;
  f32x4 acc[4] = {{0.f,0.f,0.f,0.f},{0.f,0.f,0.f,0.f},{0.f,0.f,0.f,0.f},{0.f,0.f,0.f,0.f}};
#pragma unroll
  for (int k0 = 0; k0 < 256; k0 += 32) {
    f16x8 a = *(const f16x8*)&xs[lr][k0 + lk * 8];
#pragma unroll
    for (int nt = 0; nt < 4; ++nt) {
      int n = head * 64 + nt * 16 + lr;
      f16x8 b = *(const f16x8*)(W1T + (size_t)n * 256 + k0 + lk * 8);
      acc[nt] = __builtin_amdgcn_mfma_f32_16x16x32_f16(a, b, acc[nt], 0, 0, 0);
    }
  }
#pragma unroll
  for (int nt = 0; nt < 4; ++nt) {
    int cc = nt * 16 + lr;
#pragma unroll
    for (int r = 0; r < 4; ++r) {
      int row = lk * 4 + r;
      h1h16[((size_t)head * NN + base + row) * 64 + cc] = __float2half(acc[nt][r]);
    }
  }
#pragma unroll
  for (int r = 0; r < 4; ++r) {
    float ps = 0.f, pd = 0.f;
#pragma unroll
    for (int nt = 0; nt < 4; ++nt) {
      int cc = nt * 16 + lr;
      ps += acc[nt][r] * as1[head * 64 + cc];
      pd += acc[nt][r] * ad1[head * 64 + cc];
    }
#pragma unroll
    for (int off = 1; off < 16; off <<= 1) {
      ps += __shfl_xor(ps, off);
      pd += __shfl_xor(pd, off);
    }
    if (lr == 0) {
      int n = base + lk * 4 + r;
      AS1[n * 4 + head] = ps;
      AD1[n * 4 + head] = pd;
    }
  }
}

// ---------------- GAT layer-1 agg v9: depth-2 pipeline + unroll-2 (kills rotation movs) --
__global__ __launch_bounds__(256, 4) void k_agg1(
    const int* __restrict__ rp, const int* __restrict__ col,
    const float* __restrict__ AS1, const float* __restrict__ AD1,
    const __half* __restrict__ h1h16, const float* __restrict__ b1,
    __half* __restrict__ out16) {
  int b = blockIdx.x;
  int xcd = b & 7;
  int head = xcd >> 1;
  int grp = (b >> 3) * 2 + (xcd & 1);      // 0..4999, bijective per head
  int wave = threadIdx.x >> 6, lane = threadIdx.x & 63;
  int n = grp * 4 + wave;
  int g = lane >> 3, c8 = (lane & 7) * 8;  // edge group 0..7, col base (8 fp16 = 16B)
  int e0 = rp[n], e1 = rp[n + 1];
  const __half* hs = h1h16 + (size_t)head * NN * 64;
  float adv = AD1[n * 4 + head];
  float acc[8] = {0.f,0.f,0.f,0.f,0.f,0.f,0.f,0.f};
  float den = 0.f;

  // pipeline prologue: iter0 fully loaded; iter1 index loaded
  int ee = e0 + g;
  bool vA = ee < e1;
  int ecA = vA ? ee : e1 - 1;
  int sA = col[ecA];
  float asA = AS1[sA * 4 + head];
  float4 rawA = *(const float4*)(hs + (size_t)sA * 64 + c8);

  int eeB = e0 + 8 + g;
  bool vB = eeB < e1;
  int ecB = vB ? eeB : e1 - 1;
  int sB = col[ecB];

#pragma unroll 2
  for (int e = e0; e < e1; e += 8) {
    // issue iter i+1 payload and iter i+2 index
    float asB = AS1[sB * 4 + head];
    float4 rawB = *(const float4*)(hs + (size_t)sB * 64 + c8);
    int eeC = e + 16 + g;
    bool vC = eeC < e1;
    int ecC = vC ? eeC : e1 - 1;
    int sC = col[ecC];
    // compute iter i
    float ev = asA + adv;
    ev = fmaxf(ev, NEG * ev);
    float p = vA ? __expf(ev) : 0.f;
    const f16* hf = (const f16*)&rawA;
#pragma unroll
    for (int i = 0; i < 8; ++i) acc[i] += p * (float)hf[i];    // -> v_fma_mix_f32
    den += p;
    // rotate (renamed away by unroll-2)
    sA = sB; asA = asB; rawA = rawB; vA = vB;
    sB = sC; vB = vC;
  }
#pragma unroll
  for (int i = 0; i < 8; ++i) {
    acc[i] += __shfl_xor(acc[i], 8);
    acc[i] += __shfl_xor(acc[i], 16);
    acc[i] += __shfl_xor(acc[i], 32);
  }
  den += __shfl_xor(den, 8); den += __shfl_xor(den, 16); den += __shfl_xor(den, 32);
  if (lane < 8) {
    float inv = 1.f / den;
    int cbase = head * 64 + lane * 8;
    __half ho[8];
#pragma unroll
    for (int i = 0; i < 8; ++i) {
      float r = acc[i] * inv + b1[cbase + i];
      r = r > 0.f ? r : __expf(r) - 1.f;
      ho[i] = __float2half(r);
    }
    *(uint4*)(out16 + (size_t)n * 256 + cbase) = *(uint4*)&ho[0];
  }
}

// ---------------- GEMM2 v2 (MFMA): h2 = h1act @ W2 ----------------
__global__ __launch_bounds__(256) void k_gemm2(
    const f16* __restrict__ h1a16, const f16* __restrict__ W2T,
    const float* __restrict__ as2, const float* __restrict__ ad2,
    __half* __restrict__ h2h16, float* __restrict__ AS2, float* __restrict__ AD2) {
  __shared__ f16 xs[16][264];
  __shared__ float psL[4][16], pdL[4][16];
  int tid = threadIdx.x;
  int base = blockIdx.x * 16;
  {
    int r = tid >> 4, ch = tid & 15;
    const uint4* src = (const uint4*)(h1a16 + (size_t)(base + r) * 256 + ch * 16);
    uint4 v0 = src[0], v1 = src[1];
    *(uint4*)&xs[r][ch * 16] = v0;
    *(uint4*)&xs[r][ch * 16 + 8] = v1;
  }
  __syncthreads();
  int wv = tid >> 6, lane = tid & 63;
  int lr = lane & 15, lk = lane >> 4;
  f32x4 acc = {0.f, 0.f, 0.f, 0.f};
#pragma unroll
  for (int k0 = 0; k0 < 256; k0 += 32) {
    f16x8 a = *(const f16x8*)&xs[lr][k0 + lk * 8];
    f16x8 b = *(const f16x8*)(W2T + (size_t)(wv * 16 + lr) * 256 + k0 + lk * 8);
    acc = __builtin_amdgcn_mfma_f32_16x16x32_f16(a, b, acc, 0, 0, 0);
  }
  int cc = wv * 16 + lr;
  float asv = as2[cc], adv = ad2[cc];
  float psr[4], pdr[4];
#pragma unroll
  for (int r = 0; r < 4; ++r) {
    int row = lk * 4 + r;
    h2h16[(size_t)(base + row) * 64 + cc] = __float2half(acc[r]);
    float ps = acc[r] * asv, pd = acc[r] * adv;
#pragma unroll
    for (int off = 1; off < 16; off <<= 1) {
      ps += __shfl_xor(ps, off);
      pd += __shfl_xor(pd, off);
    }
    psr[r] = ps; pdr[r] = pd;
  }
  if (lr == 0) {
#pragma unroll
    for (int r = 0; r < 4; ++r) {
      psL[wv][lk * 4 + r] = psr[r];
      pdL[wv][lk * 4 + r] = pdr[r];
    }
  }
  __syncthreads();
  if (tid < 16) {
    AS2[base + tid] = psL[0][tid] + psL[1][tid] + psL[2][tid] + psL[3][tid];
    AD2[base + tid] = pdL[0][tid] + pdL[1][tid] + pdL[2][tid] + pdL[3][tid];
  }
}

// ---------------- GAT layer-2 agg v8: depth-2 pipeline + unroll-2, fp16 out --------------
__global__ __launch_bounds__(256, 4) void k_agg2(
    const int* __restrict__ rp, const int* __restrict__ col,
    const float* __restrict__ AS2, const float* __restrict__ AD2,
    const __half* __restrict__ h2h16, const float* __restrict__ b2,
    __half* __restrict__ out16) {
  int wave = threadIdx.x >> 6, lane = threadIdx.x & 63;
  int n = blockIdx.x * 4 + wave;
  int g = lane >> 3, c8 = (lane & 7) * 8;
  int e0 = rp[n], e1 = rp[n + 1];
  float adv = AD2[n];
  float acc[8] = {0.f,0.f,0.f,0.f,0.f,0.f,0.f,0.f};
  float den = 0.f;

  int ee = e0 + g;
  bool vA = ee < e1;
  int ecA = vA ? ee : e1 - 1;
  int sA = col[ecA];
  float asA = AS2[sA];
  float4 rawA = *(const float4*)(h2h16 + (size_t)sA * 64 + c8);

  int eeB = e0 + 8 + g;
  bool vB = eeB < e1;
  int ecB = vB ? eeB : e1 - 1;
  int sB = col[ecB];

#pragma unroll 2
  for (int e = e0; e < e1; e += 8) {
    float asB = AS2[sB];
    float4 rawB = *(const float4*)(h2h16 + (size_t)sB * 64 + c8);
    int eeC = e + 16 + g;
    bool vC = eeC < e1;
    int ecC = vC ? eeC : e1 - 1;
    int sC = col[ecC];
    float ev = asA + adv;
    ev = fmaxf(ev, NEG * ev);
    float p = vA ? __expf(ev) : 0.f;
    const f16* hf = (const f16*)&rawA;
#pragma unroll
    for (int i = 0; i < 8; ++i) acc[i] += p * (float)hf[i];
    den += p;
    sA = sB; asA = asB; rawA = rawB; vA = vB;
    sB = sC; vB = vC;
  }
#pragma unroll
  for (int i = 0; i < 8; ++i) {
    acc[i] += __shfl_xor(acc[i], 8);
    acc[i] += __shfl_xor(acc[i], 16);
    acc[i] += __shfl_xor(acc[i], 32);
  }
  den += __shfl_xor(den, 8); den += __shfl_xor(den, 16); den += __shfl_xor(den, 32);
  if (lane < 8) {
    float inv = 1.f / den;
    int cbase = lane * 8;
    __half ho[8];
#pragma unroll
    for (int i = 0; i < 8; ++i) {
      float r = acc[i] * inv + b2[cbase + i];
      r = r > 0.f ? r : __expf(r) - 1.f;
      ho[i] = __float2half(r);
    }
    *(uint4*)(out16 + (size_t)n * 64 + cbase) = *(uint4*)&ho[0];
  }
}

// ---------------- predot v3 (MFMA): AB(fp16) = h2a @ [Wp1_top|Wp1_bot] (+bp1 cols<64) ----
// AB stored fp16: halves predot's write AND k_pairs' 102 MB gather stream.
__global__ __launch_bounds__(256) void k_predot(
    const f16* __restrict__ h2a16, const f16* __restrict__ Wp1cT,
    const float* __restrict__ bp1, f16* __restrict__ AB16) {
  __shared__ f16 xs[16][72];   // 16 rows x 64 k, row stride 144B (16B-aligned)
  int tid = threadIdx.x;
  int base = blockIdx.x * 16;
  {
    int r = tid >> 4, ch = tid & 15;   // thread stages 4 f16 (8B) of one row
    *(uint2*)&xs[r][ch * 4] = *(const uint2*)(h2a16 + (size_t)(base + r) * 64 + ch * 4);
  }
  __syncthreads();
  int wv = tid >> 6, lane = tid & 63;
  int lr = lane & 15, lk = lane >> 4;
#pragma unroll
  for (int t = 0; t < 2; ++t) {
    int nt = wv * 2 + t;                 // n-tile 0..7 (col block of 16)
    f32x4 acc = {0.f, 0.f, 0.f, 0.f};
#pragma unroll
    for (int k0 = 0; k0 < 64; k0 += 32) {
      f16x8 a = *(const f16x8*)&xs[lr][k0 + lk * 8];
      f16x8 b = *(const f16x8*)(Wp1cT + (size_t)(nt * 16 + lr) * 64 + k0 + lk * 8);
      acc = __builtin_amdgcn_mfma_f32_16x16x32_f16(a, b, acc, 0, 0, 0);
    }
    int c = nt * 16 + lr;                // output col 0..127
    float bb = (c < 64) ? bp1[c] : 0.f;
#pragma unroll
    for (int r = 0; r < 4; ++r) {
      int row = lk * 4 + r;
      AB16[(size_t)(base + row) * 128 + c] = (f16)(acc[r] + bb);
    }
  }
}

// ---------------- pair MLP v14: fp16 z-gather + MFMA layer 2 ----------------
__global__ __launch_bounds__(256) void k_pairs(
    const int* __restrict__ pairs, const f16* __restrict__ AB16,
    const f16* __restrict__ Wp2Th, const float* __restrict__ bp2p,
    float* __restrict__ out) {
  __shared__ f16 zh[64][72];  // [pair][t]
  int tid = threadIdx.x;
  int pp = tid & 63, q = tid >> 6;   // pair within block, z-quarter
  int p = blockIdx.x * 64 + pp;
  int pi = pairs[2 * p], pj = pairs[2 * p + 1];

  // ---- phase 1: z quarter q = relu(A[pi] + B[pj]) -> fp16 LDS  (bp1 folded in A)
  {
    const f16* aP = AB16 + (size_t)pi * 128 + q * 16;
    const f16* bP = AB16 + (size_t)pj * 128 + 64 + q * 16;
    f16x8 a0 = *(const f16x8*)aP, a1 = *(const f16x8*)(aP + 8);
    f16x8 b0 = *(const f16x8*)bP, b1 = *(const f16x8*)(bP + 8);
    f16 zv[16];
#pragma unroll
    for (int m = 0; m < 8; ++m) {
      f16 s0 = (f16)(a0[m] + b0[m]);
      f16 s1 = (f16)(a1[m] + b1[m]);
      zv[m]     = s0 > (f16)0.f ? s0 : (f16)0.f;
      zv[m + 8] = s1 > (f16)0.f ? s1 : (f16)0.f;
    }
    *(uint4*)&zh[pp][q * 16] = *(uint4*)&zv[0];
    *(uint4*)&zh[pp][q * 16 + 8] = *(uint4*)&zv[8];
  }
  __syncthreads();

  // ---- phase 2: out-tile = z @ Wp2 via MFMA; wave wv owns pairs wv*16..wv*16+15
  int wv = tid >> 6, lane = tid & 63;
  int lr = lane & 15, lk = lane >> 4;
#pragma unroll
  for (int nt = 0; nt < 6; ++nt) {
    f32x4 acc = {0.f, 0.f, 0.f, 0.f};
#pragma unroll
    for (int k0 = 0; k0 < 64; k0 += 32) {
      f16x8 a = *(const f16x8*)&zh[wv * 16 + lr][k0 + lk * 8];
      f16x8 b = *(const f16x8*)(Wp2Th + (size_t)(nt * 16 + lr) * 64 + k0 + lk * 8);
      acc = __builtin_amdgcn_mfma_f32_16x16x32_f16(a, b, acc, 0, 0, 0);
    }
    int o = nt * 16 + lr;
    if (o < 86) {
      float bb = bp2p[o];
#pragma unroll
      for (int r = 0; r < 4; ++r) {
        int pr = blockIdx.x * 64 + wv * 16 + lk * 4 + r;
        out[(size_t)pr * 86 + o] = acc[r] + bb;
      }
    }
  }
}

extern "C" void kernel_launch(void* const* d_in, const int* in_sizes, int n_in,
                              void* d_out, int out_size, void* d_ws, size_t ws_size,
                              hipStream_t stream) {
  (void)in_sizes; (void)n_in; (void)out_size; (void)ws_size;
  const float* x      = (const float*)d_in[0];
  const int*   ei     = (const int*)d_in[1];
  const int*   pairs  = (const int*)d_in[2];
  const float* W1     = (const float*)d_in[3];
  const float* a_src1 = (const float*)d_in[4];
  const float* a_dst1 = (const float*)d_in[5];
  const float* b1     = (const float*)d_in[6];
  const float* W2     = (const float*)d_in[7];
  const float* a_src2 = (const float*)d_in[8];
  const float* a_dst2 = (const float*)d_in[9];
  const float* b2     = (const float*)d_in[10];
  const float* Wp1    = (const float*)d_in[11];
  const float* bp1    = (const float*)d_in[12];
  const float* Wp2    = (const float*)d_in[13];
  const float* bp2    = (const float*)d_in[14];
  float* out = (float*)d_out;

  char* w = (char*)d_ws;
  auto alloc = [&](size_t bytes) -> void* {
    void* pp = (void*)w;
    w += (bytes + 255) & ~(size_t)255;
    return pp;
  };
  __half* h1h16 = (__half*)alloc((size_t)NN * 256 * 2);  // head-major [4][NN][64] fp16
  float*  AS1   = (float*)alloc((size_t)NN * 4 * 4);
  float*  AD1   = (float*)alloc((size_t)NN * 4 * 4);
  __half* h1a16 = (__half*)alloc((size_t)NN * 256 * 2);  // fp16 h1agg (gemm2 input)
  __half* h2h16 = (__half*)alloc((size_t)NN * 64 * 2);   // fp16 gather copy
  float*  AS2   = (float*)alloc((size_t)NN * 4);
  float*  AD2   = (float*)alloc((size_t)NN * 4);
  __half* h2a16 = (__half*)alloc((size_t)NN * 64 * 2);   // fp16 h2agg (predot input)
  f16*    AB16  = (f16*)alloc((size_t)NN * 128 * 2);     // fp16 AB (pairs input)
  f16*    W1T   = (f16*)alloc((size_t)256 * 256 * 2);    // fp16 W1 transposed [n][k]
  f16*    Wp2Th = (f16*)alloc((size_t)96 * 64 * 2);      // fp16 Wp2 transposed padded
  float*  bp2p  = (float*)alloc(96 * 4);
  f16*    W2T   = (f16*)alloc((size_t)64 * 256 * 2);     // fp16 W2 transposed [n][k]
  f16*    Wp1cT = (f16*)alloc((size_t)128 * 64 * 2);     // fp16 concat-folded Wp1 [c][k]
  int*    rp    = (int*)alloc((size_t)(NN + 1) * 4);
  int*    cnt   = (int*)alloc((size_t)NN * 4);
  int*    cur   = (int*)alloc((size_t)NN * 4);
  int*    col   = (int*)alloc((size_t)NEE * 4);

  (void)hipMemsetAsync(cnt, 0, (size_t)NN * 4, stream);
  (void)hipMemsetAsync(cur, 0, (size_t)NN * 4, stream);

  k_hist<<<NCHUNK * 8, 256, 0, stream>>>(ei, cnt);
  k_scan<<<1, 1024, 0, stream>>>(cnt, rp);
  k_scatter<<<NCHUNK * 8, 256, 0, stream>>>(ei, rp, cur, col);
  k_prep<<<256, 256, 0, stream>>>(Wp2, bp2, W2, W1, Wp1, Wp2Th, bp2p, W2T, W1T, Wp1cT);

  k_gemm1<<<NN / 16, 256, 0, stream>>>(x, W1T, a_src1, a_dst1, h1h16, AS1, AD1);
  k_agg1<<<NN, 256, 0, stream>>>(rp, col, AS1, AD1, h1h16, b1, h1a16);

  k_gemm2<<<NN / 16, 256, 0, stream>>>((const f16*)h1a16, W2T, a_src2, a_dst2, h2h16, AS2, AD2);
  k_agg2<<<NN / 4, 256, 0, stream>>>(rp, col, AS2, AD2, h2h16, b2, h2a16);

  k_predot<<<NN / 16, 256, 0, stream>>>((const f16*)h2a16, Wp1cT, bp1, AB16);
  k_pairs<<<NP / 64, 256, 0, stream>>>(pairs, AB16, Wp2Th, bp2p, out);
}